// Round 17
// baseline (3907.545 us; speedup 1.0000x reference)
//
#include <hip/hip_runtime.h>

#define LEAKY(v) ((v) >= 0.f ? (v) : 0.01f * (v))

#define CS   4608      // ring channel stride in floats (18 rows * 256)
#define ZS1  294912    // ring tower stride (64 * CS)
#define TSL  16        // top-pad slot
#define BSL  17        // bottom-pad slot
#define EBCS 7936      // ebuf channel stride (31*256)
#define NWG  384
#define S16(c) ((c) & 15)

// ================= bootstrap kernels (validated, round 14) =================
__global__ __launch_bounds__(256, 2) void conv3B(
    const float* __restrict__ ebuf,
    const float* __restrict__ W0, const float* __restrict__ B0,
    const float* __restrict__ W1, const float* __restrict__ B1,
    float* __restrict__ out)
{
    const int lane = threadIdx.x & 63;
    const int wv   = threadIdx.x >> 6;
    const int h  = blockIdx.y;
    const int cq = blockIdx.z & 3;
    const int z  = blockIdx.z >> 2;
    const int cout0 = cq * 16 + wv * 4;
    const float* W  = (z ? W1 : W0) + cout0 * 27;
    const float* Bv = z ? B1 : B0;

    float a[4][4] = {};
    #pragma unroll
    for (int kh = 0; kh < 3; ++kh) {
        const int r = h - 1 + kh;
        const bool valid = (r >= 0 && r < 15);
        const float msk = valid ? 1.f : 0.f;
        #pragma unroll
        for (int c = 0; c < 3; ++c) {
            const float* rr = ebuf + c * EBCS + (valid ? r : 0) * 256 + lane * 4;
            float4 v = *(const float4*)rr;
            v.x *= msk; v.y *= msk; v.z *= msk; v.w *= msk;
            float wl = __shfl_up(v.w, 1);   if (lane == 0)  wl = 0.f;
            float wr = __shfl_down(v.x, 1); if (lane == 63) wr = 0.f;
            const float win[6] = {wl, v.x, v.y, v.z, v.w, wr};
            #pragma unroll
            for (int j = 0; j < 4; ++j) {
                const float* wj = W + j * 27 + c * 9 + kh * 3;
                #pragma unroll
                for (int cc = 0; cc < 4; ++cc)
                    a[j][cc] += wj[0] * win[cc] + wj[1] * win[cc + 1] + wj[2] * win[cc + 2];
            }
        }
    }
    const int slot = (h == 0) ? TSL : (h == 14 ? BSL : (h & 15));
    float* o = out + (size_t)z * ZS1 + slot * 256;
    #pragma unroll
    for (int j = 0; j < 4; ++j) {
        const float bb = Bv[cout0 + j];
        float4 r4;
        r4.x = LEAKY(a[j][0] + bb); r4.y = LEAKY(a[j][1] + bb);
        r4.z = LEAKY(a[j][2] + bb); r4.w = LEAKY(a[j][3] + bb);
        *(float4*)(o + (cout0 + j) * CS + lane * 4) = r4;
    }
}

template<int HOUT, int HIN, int OFFI, int OFFO, int NZ>
__global__ __launch_bounds__(256, 2) void convYB(
    const float* __restrict__ in,
    const float* __restrict__ W0, const float* __restrict__ B0,
    const float* __restrict__ W1, const float* __restrict__ B1,
    float* __restrict__ out)
{
    const int lane = threadIdx.x;
    const int y    = threadIdx.y;
    const int h  = blockIdx.y;
    const int gz = blockIdx.z;
    const int z    = (NZ == 2) ? (gz >> 6) : 0;
    const int cout = (NZ == 2) ? (gz & 63) : gz;
    const float* W  = (z ? W1 : W0) + cout * 576 + y * 144;
    const float* Bv = z ? B1 : B0;
    const float* ib = in + (size_t)z * ZS1 + y * 16 * CS + lane * 4;

    int slot[3];
    #pragma unroll
    for (int t = 0; t < 3; ++t) {
        const int g = h + t;
        slot[t] = (g == 0) ? TSL : (g == HIN - 1 ? BSL : ((g + OFFI) & 15));
    }

    float acc[4] = {};
    #pragma unroll 4
    for (int c = 0; c < 16; ++c) {
        #pragma unroll
        for (int t = 0; t < 3; ++t) {
            float4 v = *(const float4*)(ib + c * CS + slot[t] * 256);
            float wl = __shfl_up(v.w, 1);   if (lane == 0)  wl = 0.f;
            float wr = __shfl_down(v.x, 1); if (lane == 63) wr = 0.f;
            const float win[6] = {wl, v.x, v.y, v.z, v.w, wr};
            const float* wj = W + c * 9 + t * 3;
            #pragma unroll
            for (int cc = 0; cc < 4; ++cc)
                acc[cc] += wj[0] * win[cc] + wj[1] * win[cc + 1] + wj[2] * win[cc + 2];
        }
    }

    __shared__ float red[4][256];
    *(float4*)&red[y][lane * 4] = *(float4*)acc;
    __syncthreads();
    const int col = y * 64 + lane;
    const int os = (h == 0) ? TSL : (h == HOUT - 1 ? BSL : ((h + OFFO) & 15));
    float v = Bv[cout] + red[0][col] + red[1][col] + red[2][col] + red[3][col];
    out[(size_t)z * ZS1 + cout * CS + os * 256 + col] = LEAKY(v);
}

__global__ __launch_bounds__(256, 2) void mmB(const float* __restrict__ L4R,
                                              float* __restrict__ MMR)
{
    const int col = threadIdx.x;
    const int r   = blockIdx.x;
    const int ig  = blockIdx.y;
    const int slot = (r == 0) ? TSL : (r == 8 ? BSL : ((r + 3) & 15));
    const float* s = L4R + slot * 256 + col;
    const float* e = L4R + ZS1 + slot * 256 + col;
    float sv[64];
    #pragma unroll
    for (int c = 0; c < 64; ++c) sv[c] = s[c * CS];
    float ev[8];
    #pragma unroll
    for (int j = 0; j < 8; ++j) ev[j] = e[(ig * 8 + j) * CS];
    #pragma unroll
    for (int k = 0; k < 8; ++k) {
        float acc = 0.f;
        #pragma unroll
        for (int j = 0; j < 8; ++j) acc += ev[j] * sv[j * 8 + k];
        MMR[(ig * 8 + k) * CS + slot * 256 + col] = acc;
    }
}

// ================= persistent stepper =================
struct SP {
    const float *x;
    const float *w1x, *b1x, *w2x, *b2x, *w3x, *b3x, *w4x, *b4x;
    const float *w1e, *b1e, *w2e, *b2e, *w3e, *b3e, *w4e, *b4e;
    const float *w5, *b5, *w6, *b6, *w7, *b7, *w8, *b8, *w9, *b9;
    float *ebuf, *L1R, *L2R, *L3R, *L4R, *MMR, *L5R, *L6R, *L7b, *L8b, *preds, *out;
    unsigned *bar;
};

// Two-level grid barrier: 6 group counters (separate 128B lines) + master + gen.
// RELAXED polling; one release fence before arrival, one acquire after flip.
__device__ __forceinline__ void gbar(unsigned* bar, int wg)
{
    __syncthreads();
    if (threadIdx.x == 0 && threadIdx.y == 0) {
        __threadfence();   // release
        unsigned* gcnt   = bar + (wg >> 6) * 32;   // 6 groups of 64 wgs
        unsigned* master = bar + 192;
        unsigned* gen    = bar + 224;
        unsigned g = __hip_atomic_load(gen, __ATOMIC_RELAXED, __HIP_MEMORY_SCOPE_AGENT);
        unsigned v = __hip_atomic_fetch_add(gcnt, 1u, __ATOMIC_ACQ_REL, __HIP_MEMORY_SCOPE_AGENT);
        if (v == 63) {
            __hip_atomic_store(gcnt, 0u, __ATOMIC_RELAXED, __HIP_MEMORY_SCOPE_AGENT);
            unsigned m = __hip_atomic_fetch_add(master, 1u, __ATOMIC_ACQ_REL, __HIP_MEMORY_SCOPE_AGENT);
            if (m == 5) {
                __hip_atomic_store(master, 0u, __ATOMIC_RELAXED, __HIP_MEMORY_SCOPE_AGENT);
                __hip_atomic_store(gen, g + 1u, __ATOMIC_RELEASE, __HIP_MEMORY_SCOPE_AGENT);
            } else {
                while (__hip_atomic_load(gen, __ATOMIC_RELAXED, __HIP_MEMORY_SCOPE_AGENT) == g)
                    __builtin_amdgcn_s_sleep(2);
            }
        } else {
            while (__hip_atomic_load(gen, __ATOMIC_RELAXED, __HIP_MEMORY_SCOPE_AGENT) == g)
                __builtin_amdgcn_s_sleep(2);
        }
        __threadfence();   // acquire
    }
    __syncthreads();
}

// one fresh conv row; (64,8) block: wave y handles 8 cins -> 2 dependent
// load groups (unroll 4). W in LDS.
__device__ __forceinline__ void convRowD8(
    const float* __restrict__ t0, const float* __restrict__ t1, const float* __restrict__ t2,
    const float* W, float bb, float* __restrict__ orow, int ics,
    float (*red)[256])
{
    const int lane = threadIdx.x, y = threadIdx.y;
    const float* Wy = W + y * 72;           // 8 cins * 9 taps
    const int yo = y * 8 * ics + lane * 4;
    const float* p0 = t0 + yo;
    const float* p1 = t1 + yo;
    const float* p2 = t2 + yo;

    float acc[4] = {};
    #pragma unroll 4
    for (int c = 0; c < 8; ++c) {
        #pragma unroll
        for (int t = 0; t < 3; ++t) {
            const float* rp = (t == 0 ? p0 : (t == 1 ? p1 : p2)) + c * ics;
            float4 v = *(const float4*)rp;
            float wl = __shfl_up(v.w, 1);   if (lane == 0)  wl = 0.f;
            float wr = __shfl_down(v.x, 1); if (lane == 63) wr = 0.f;
            const float win[6] = {wl, v.x, v.y, v.z, v.w, wr};
            const float* wj = Wy + c * 9 + t * 3;
            #pragma unroll
            for (int cc = 0; cc < 4; ++cc)
                acc[cc] += wj[0] * win[cc] + wj[1] * win[cc + 1] + wj[2] * win[cc + 2];
        }
    }
    __syncthreads();
    *(float4*)&red[y][lane * 4] = *(float4*)acc;
    __syncthreads();
    const int flat = y * 64 + lane;
    if (flat < 256) {
        float v = bb;
        #pragma unroll
        for (int yy = 0; yy < 8; ++yy) v += red[yy][flat];
        orow[flat] = LEAKY(v);
    }
}

__device__ __forceinline__ void phaseL1(const SP& p, int i, int wg,
                                        const float* wl1, const float* bb1)
{
    if (wg >= 24) return;
    const int lane = threadIdx.x, wv = threadIdx.y;   // wv 0..7 -> 2 couts each
    const int job = wg >> 3, z = (wg >> 2) & 1, cq = wg & 3;
    const float* taps[3];
    int os;
    if (job == 0)      { taps[0] = nullptr;                  taps[1] = p.ebuf + i * 256;        taps[2] = p.ebuf + (i + 1) * 256;  os = TSL; }
    else if (job == 1) { taps[0] = p.ebuf + (i + 13) * 256;  taps[1] = p.ebuf + (i + 14) * 256; taps[2] = nullptr;                 os = BSL; }
    else               { taps[0] = p.ebuf + (i + 12) * 256;  taps[1] = p.ebuf + (i + 13) * 256; taps[2] = p.ebuf + (i + 14) * 256; os = S16(i + 13); }
    const int cout0 = cq * 16 + wv * 2;
    const float* W = wl1 + (wv * 2) * 27;

    float a[2][4] = {};
    #pragma unroll
    for (int t = 0; t < 3; ++t) {
        const float* rp = taps[t];
        if (rp) {
            #pragma unroll
            for (int c = 0; c < 3; ++c) {
                float4 v = *(const float4*)(rp + c * EBCS + lane * 4);
                float wl = __shfl_up(v.w, 1);   if (lane == 0)  wl = 0.f;
                float wr = __shfl_down(v.x, 1); if (lane == 63) wr = 0.f;
                const float win[6] = {wl, v.x, v.y, v.z, v.w, wr};
                #pragma unroll
                for (int j = 0; j < 2; ++j) {
                    const float* wj = W + j * 27 + c * 9 + t * 3;
                    #pragma unroll
                    for (int cc = 0; cc < 4; ++cc)
                        a[j][cc] += wj[0] * win[cc] + wj[1] * win[cc + 1] + wj[2] * win[cc + 2];
                }
            }
        }
    }
    float* o = p.L1R + (size_t)z * ZS1 + os * 256;
    #pragma unroll
    for (int j = 0; j < 2; ++j) {
        const float bb = bb1[wv * 2 + j];
        float4 r4;
        r4.x = LEAKY(a[j][0] + bb); r4.y = LEAKY(a[j][1] + bb);
        r4.z = LEAKY(a[j][2] + bb); r4.w = LEAKY(a[j][3] + bb);
        *(float4*)(o + (cout0 + j) * CS + lane * 4) = r4;
    }
}

// 384 units exactly: vb = wg. cout = wg&63, q = wg>>6: z = q&1, jt = q>>1.
__device__ __forceinline__ void phase2t(
    int i, int d, const float* inR, float* outR,
    const float* Wl, float bbv, int wg, float (*red)[256])
{
    const int cout = wg & 63, q = wg >> 6;
    const int z = q & 1, jt = q >> 1;
    const float* base = inR + (size_t)z * ZS1;
    const float* t0; const float* t1; const float* t2; int os;
    if (jt == 0)      { t0 = base + TSL * 256;              t1 = base + S16(i + d) * 256;      t2 = base + S16(i + d + 1) * 256;  os = TSL; }
    else if (jt == 1) { t0 = base + S16(i + 13 - d) * 256;  t1 = base + S16(i + 14 - d) * 256; t2 = base + BSL * 256;             os = BSL; }
    else              { t0 = base + S16(i + 12 - d) * 256;  t1 = base + S16(i + 13 - d) * 256; t2 = base + S16(i + 14 - d) * 256; os = S16(i + 13 - d); }
    convRowD8(t0, t1, t2, Wl, bbv,
              outR + (size_t)z * ZS1 + cout * CS + os * 256, CS, red);
}

__device__ __forceinline__ void phase1t(
    int i, int d, const float* inR, float* outR,
    const float* Wl, float bbv, int wg, float (*red)[256])
{
    if (wg >= 192) return;
    const int cout = wg & 63, jt = wg >> 6;
    const float* t0; const float* t1; const float* t2; int os;
    if (jt == 0)      { t0 = inR + TSL * 256;              t1 = inR + S16(i + d) * 256;      t2 = inR + S16(i + d + 1) * 256;  os = TSL; }
    else if (jt == 1) { t0 = inR + S16(i + 13 - d) * 256;  t1 = inR + S16(i + 14 - d) * 256; t2 = inR + BSL * 256;             os = BSL; }
    else              { t0 = inR + S16(i + 12 - d) * 256;  t1 = inR + S16(i + 13 - d) * 256; t2 = inR + S16(i + 14 - d) * 256; os = S16(i + 13 - d); }
    convRowD8(t0, t1, t2, Wl, bbv,
              outR + cout * CS + os * 256, CS, red);
}

__device__ __forceinline__ void phaseMM(const SP& p, int i, int wg)
{
    if (wg >= 24) return;
    const int flat = threadIdx.y * 64 + threadIdx.x;
    if (flat >= 256) return;
    const int col = flat;
    const int job = wg >> 3, ig = wg & 7;
    const int slot = (job == 0) ? TSL : (job == 1 ? BSL : S16(i + 10));
    const float* s = p.L4R + slot * 256 + col;
    const float* e = p.L4R + ZS1 + slot * 256 + col;
    float sv[64];
    #pragma unroll
    for (int c = 0; c < 64; ++c) sv[c] = s[c * CS];
    float ev[8];
    #pragma unroll
    for (int j = 0; j < 8; ++j) ev[j] = e[(ig * 8 + j) * CS];
    #pragma unroll
    for (int k = 0; k < 8; ++k) {
        float acc = 0.f;
        #pragma unroll
        for (int j = 0; j < 8; ++j) acc += ev[j] * sv[j * 8 + k];
        p.MMR[(ig * 8 + k) * CS + slot * 256 + col] = acc;
    }
}

__device__ __forceinline__ void phaseL7(const SP& p, int i, const float* Wl, float bbv,
                                        int wg, float (*red)[256])
{
    if (wg >= 192) return;
    const int cout = wg & 63, jt = wg >> 6;
    const float* t0; const float* t1; const float* t2;
    if (jt == 0)      { t0 = p.L6R + TSL * 256;          t1 = p.L6R + S16(i + 6) * 256; t2 = p.L6R + S16(i + 7) * 256; }
    else if (jt == 1) { t0 = p.L6R + S16(i + 6) * 256;   t1 = p.L6R + S16(i + 7) * 256; t2 = p.L6R + S16(i + 8) * 256; }
    else              { t0 = p.L6R + S16(i + 7) * 256;   t1 = p.L6R + S16(i + 8) * 256; t2 = p.L6R + BSL * 256; }
    convRowD8(t0, t1, t2, Wl, bbv,
              p.L7b + jt * 256 + cout * 768, CS, red);
}

__device__ __forceinline__ void phaseL8(const SP& p, const float* Wl, float bbv,
                                        int wg, float (*red)[256])
{
    if (wg >= 64) return;
    convRowD8(p.L7b, p.L7b + 256, p.L7b + 512, Wl, bbv,
              p.L8b + wg * 256, 768, red);
}

__device__ __forceinline__ void dC9(const SP& p, int i, const float* wl9, const float* bb9,
                                    float (*red9)[3][256])
{
    const int flat = threadIdx.y * 64 + threadIdx.x;
    const int grp = flat >> 8, col = flat & 255;   // 2 groups x 32 cins
    const bool mL = (col > 0), mR = (col < 255);
    float a0 = 0.f, a1 = 0.f, a2 = 0.f;
    const int c0 = grp * 32;
    #pragma unroll 4
    for (int c = 0; c < 32; ++c) {
        const int cin = c0 + c;
        const float* r_ = p.L8b + cin * 256;
        float vm = mL ? r_[col - 1] : 0.f;
        float v0 = r_[col];
        float vp = mR ? r_[col + 1] : 0.f;
        const float* wk0 = wl9 + (0 * 64 + cin) * 9 + 3;
        const float* wk1 = wl9 + (1 * 64 + cin) * 9 + 3;
        const float* wk2 = wl9 + (2 * 64 + cin) * 9 + 3;
        a0 += vm * wk0[0] + v0 * wk0[1] + vp * wk0[2];
        a1 += vm * wk1[0] + v0 * wk1[1] + vp * wk1[2];
        a2 += vm * wk2[0] + v0 * wk2[1] + vp * wk2[2];
    }
    __syncthreads();
    red9[grp][0][col] = a0;
    red9[grp][1][col] = a1;
    red9[grp][2][col] = a2;
    __syncthreads();
    if (grp == 0) {
        #pragma unroll
        for (int j = 0; j < 3; ++j) {
            float v = LEAKY(bb9[j] + red9[0][j][col] + red9[1][j][col]);
            p.preds[i * 768 + j * 256 + col] = v;
            p.ebuf[j * EBCS + (15 + i) * 256 + col] =
                p.x[j * EBCS + (15 + i) * 256 + col] - v;
        }
    }
}

__global__ __launch_bounds__(512, 4) void stepper(SP p)
{
    __shared__ float red[8][256];       // 8 KB
    __shared__ float wl[7 * 576];       // 15.75 KB
    __shared__ float wl1[432];          // wg<24
    __shared__ float wl9[1728];         // wg 0
    __shared__ float red9[2][3][256];   // 6 KB
    __shared__ float bbs[8];
    __shared__ float bb1[16];
    __shared__ float bb9[3];

    const int wg = blockIdx.x;
    const int flat = threadIdx.y * 64 + threadIdx.x;

    // ---- one-time weight preload into LDS ----
    const int zt = (wg >> 6) & 1;     // tower for this wg's phase2t unit
    const int co = wg & 63;
    for (int k = flat; k < 576; k += 512) {
        wl[0 * 576 + k] = (zt ? p.w2e : p.w2x)[co * 576 + k];
        wl[1 * 576 + k] = (zt ? p.w3e : p.w3x)[co * 576 + k];
        wl[2 * 576 + k] = (zt ? p.w4e : p.w4x)[co * 576 + k];
        wl[3 * 576 + k] = p.w5[co * 576 + k];
        wl[4 * 576 + k] = p.w6[co * 576 + k];
        wl[5 * 576 + k] = p.w7[co * 576 + k];
        wl[6 * 576 + k] = p.w8[co * 576 + k];
    }
    if (wg < 24) {
        const int z1 = (wg >> 2) & 1, cq = wg & 3;
        for (int k = flat; k < 432; k += 512)
            wl1[k] = (z1 ? p.w1e : p.w1x)[cq * 16 * 27 + k];
        if (flat < 16) bb1[flat] = (z1 ? p.b1e : p.b1x)[cq * 16 + flat];
    }
    if (wg == 0) {
        for (int k = flat; k < 1728; k += 512) wl9[k] = p.w9[k];
        if (flat < 3) bb9[flat] = p.b9[flat];
    }
    if (flat == 0) {
        bbs[0] = (zt ? p.b2e : p.b2x)[co];
        bbs[1] = (zt ? p.b3e : p.b3x)[co];
        bbs[2] = (zt ? p.b4e : p.b4x)[co];
        bbs[3] = p.b5[co];
        bbs[4] = p.b6[co];
        bbs[5] = p.b7[co];
        bbs[6] = p.b8[co];
    }
    __syncthreads();

    // step 0 tail (bootstrap covered L1..L6)
    phaseL7(p, 0, wl + 5 * 576, bbs[5], wg, red);  gbar(p.bar, wg);
    phaseL8(p, wl + 6 * 576, bbs[6], wg, red);     gbar(p.bar, wg);
    if (wg == 0) dC9(p, 0, wl9, bb9, red9);        gbar(p.bar, wg);

    for (int i = 1; i < 16; ++i) {
        phaseL1(p, i, wg, wl1, bb1);                                 gbar(p.bar, wg);
        phase2t(i, 1, p.L1R, p.L2R, wl + 0 * 576, bbs[0], wg, red);  gbar(p.bar, wg);
        phase2t(i, 2, p.L2R, p.L3R, wl + 1 * 576, bbs[1], wg, red);  gbar(p.bar, wg);
        phase2t(i, 3, p.L3R, p.L4R, wl + 2 * 576, bbs[2], wg, red);  gbar(p.bar, wg);
        phaseMM(p, i, wg);                                           gbar(p.bar, wg);
        phase1t(i, 4, p.MMR, p.L5R, wl + 3 * 576, bbs[3], wg, red);  gbar(p.bar, wg);
        phase1t(i, 5, p.L5R, p.L6R, wl + 4 * 576, bbs[4], wg, red);  gbar(p.bar, wg);
        phaseL7(p, i, wl + 5 * 576, bbs[5], wg, red);                gbar(p.bar, wg);
        phaseL8(p, wl + 6 * 576, bbs[6], wg, red);                   gbar(p.bar, wg);
        if (wg == 0) dC9(p, i, wl9, bb9, red9);                      gbar(p.bar, wg);
    }

    // finalize: d_out = [pred (3,16,256) | truth (3,16,256)]
    for (int idx = wg * 512 + flat; idx < 24576; idx += NWG * 512) {
        if (idx < 12288) {
            const int c = idx >> 12;
            const int t = (idx >> 8) & 15;
            const int w = idx & 255;
            p.out[idx] = p.preds[t * 768 + c * 256 + w];
        } else {
            const int j = idx - 12288;
            const int c = j >> 12;
            const int t = (j >> 8) & 15;
            const int w = j & 255;
            p.out[idx] = p.ebuf[c * EBCS + (15 + t) * 256 + w];
        }
    }
}

extern "C" void kernel_launch(void* const* d_in, const int* in_sizes, int n_in,
                              void* d_out, int out_size, void* d_ws, size_t ws_size,
                              hipStream_t stream)
{
    SP p;
    p.x   = (const float*)d_in[0];
    p.w1x = (const float*)d_in[1];  p.b1x = (const float*)d_in[2];
    p.w2x = (const float*)d_in[3];  p.b2x = (const float*)d_in[4];
    p.w3x = (const float*)d_in[5];  p.b3x = (const float*)d_in[6];
    p.w4x = (const float*)d_in[7];  p.b4x = (const float*)d_in[8];
    p.w1e = (const float*)d_in[9];  p.b1e = (const float*)d_in[10];
    p.w2e = (const float*)d_in[11]; p.b2e = (const float*)d_in[12];
    p.w3e = (const float*)d_in[13]; p.b3e = (const float*)d_in[14];
    p.w4e = (const float*)d_in[15]; p.b4e = (const float*)d_in[16];
    p.w5  = (const float*)d_in[17]; p.b5  = (const float*)d_in[18];
    p.w6  = (const float*)d_in[19]; p.b6  = (const float*)d_in[20];
    p.w7  = (const float*)d_in[21]; p.b7  = (const float*)d_in[22];
    p.w8  = (const float*)d_in[23]; p.b8  = (const float*)d_in[24];
    p.w9  = (const float*)d_in[25]; p.b9  = (const float*)d_in[26];

    float* ws = (float*)d_ws;
    p.ebuf  = ws;
    p.L1R   = p.ebuf + 23808;
    p.L2R   = p.L1R + 589824;
    p.L3R   = p.L2R + 589824;
    p.L4R   = p.L3R + 589824;
    p.MMR   = p.L4R + 589824;
    p.L5R   = p.MMR + 294912;
    p.L6R   = p.L5R + 294912;
    p.L7b   = p.L6R + 294912;
    p.L8b   = p.L7b + 49152;
    p.preds = p.L8b + 16384;
    p.bar   = (unsigned*)(p.preds + 12288);
    p.out   = (float*)d_out;

    hipMemsetAsync(p.bar, 0, 256 * sizeof(unsigned), stream);
    hipMemcpyAsync(p.ebuf, p.x, 23808 * sizeof(float), hipMemcpyDeviceToDevice, stream);

    const dim3 cb(64, 4);
    conv3B<<<dim3(1, 15, 8), 256, 0, stream>>>(p.ebuf, p.w1x, p.b1x, p.w1e, p.b1e, p.L1R);
    convYB<13, 15, 0, 1, 2><<<dim3(1, 13, 128), cb, 0, stream>>>(p.L1R, p.w2x, p.b2x, p.w2e, p.b2e, p.L2R);
    convYB<11, 13, 1, 2, 2><<<dim3(1, 11, 128), cb, 0, stream>>>(p.L2R, p.w3x, p.b3x, p.w3e, p.b3e, p.L3R);
    convYB<9, 11, 2, 3, 2><<<dim3(1, 9, 128), cb, 0, stream>>>(p.L3R, p.w4x, p.b4x, p.w4e, p.b4e, p.L4R);
    mmB<<<dim3(9, 8), 256, 0, stream>>>(p.L4R, p.MMR);
    convYB<7, 9, 3, 4, 1><<<dim3(1, 7, 64), cb, 0, stream>>>(p.MMR, p.w5, p.b5, p.w5, p.b5, p.L5R);
    convYB<5, 7, 4, 5, 1><<<dim3(1, 5, 64), cb, 0, stream>>>(p.L5R, p.w6, p.b6, p.w6, p.b6, p.L6R);

    stepper<<<NWG, dim3(64, 8), 0, stream>>>(p);
}

// Round 18
// 2724.605 us; speedup vs baseline: 1.4342x; 1.4342x over previous
//
#include <hip/hip_runtime.h>

#define LEAKY(v) ((v) >= 0.f ? (v) : 0.01f * (v))

#define CS   4608      // ring channel stride in floats (18 rows * 256)
#define ZS1  294912    // ring tower stride (64 * CS)
#define TSL  16        // top-pad slot
#define BSL  17        // bottom-pad slot
#define EBCS 7936      // ebuf channel stride (31*256)
#define S16(c) ((c) & 15)

// ================= generic incremental CIN=64 conv (round 14, verbatim) =================
struct JobD { const float* t0; const float* t1; const float* t2; float* o; };
struct IncP { JobD jd[6]; };

__global__ __launch_bounds__(256, 2) void convInc(
    IncP P, const float* __restrict__ W0, const float* __restrict__ B0,
    const float* __restrict__ W1, const float* __restrict__ B1,
    int zsel, int ics, int ocs)
{
    const int lane = threadIdx.x;
    const int y    = threadIdx.y;
    const int q    = blockIdx.x >> 6;
    const int cout = blockIdx.x & 63;
    const int z    = (zsel >> q) & 1;
    const float* W  = (z ? W1 : W0) + cout * 576 + y * 144;
    const float* Bv = z ? B1 : B0;
    const JobD jd  = P.jd[q];
    const int yo   = y * 16 * ics + lane * 4;
    const float* t0 = jd.t0 + yo;
    const float* t1 = jd.t1 + yo;
    const float* t2 = jd.t2 + yo;

    float acc[4] = {};
    #pragma unroll 4
    for (int c = 0; c < 16; ++c) {
        #pragma unroll
        for (int t = 0; t < 3; ++t) {
            const float* rp = (t == 0 ? t0 : (t == 1 ? t1 : t2)) + c * ics;
            float4 v = *(const float4*)rp;
            float wl = __shfl_up(v.w, 1);   if (lane == 0)  wl = 0.f;
            float wr = __shfl_down(v.x, 1); if (lane == 63) wr = 0.f;
            const float win[6] = {wl, v.x, v.y, v.z, v.w, wr};
            const float* wj = W + c * 9 + t * 3;
            #pragma unroll
            for (int cc = 0; cc < 4; ++cc)
                acc[cc] += wj[0] * win[cc] + wj[1] * win[cc + 1] + wj[2] * win[cc + 2];
        }
    }

    __shared__ float red[4][256];
    *(float4*)&red[y][lane * 4] = *(float4*)acc;
    __syncthreads();
    const int col = y * 64 + lane;
    float v = Bv[cout] + red[0][col] + red[1][col] + red[2][col] + red[3][col];
    jd.o[cout * ocs + col] = LEAKY(v);
}

// ================= fused conv9(i-1) + L1(i) =================
// grid 24 blocks of 256. Phase A: every block recomputes conv9(i-1) from L8b
// into eL (redundant, private); block 0 persists preds row i-1 and ebuf row i+14.
// Phase B: conv3inc (round 14) with taps hitting row i+14 redirected to eL.
__global__ __launch_bounds__(256, 2) void fusedL1(
    const float* __restrict__ L8b, const float* __restrict__ w9,
    const float* __restrict__ b9, const float* __restrict__ x,
    float* __restrict__ ebuf, float* __restrict__ preds,
    const float* __restrict__ W0, const float* __restrict__ B0,
    const float* __restrict__ W1, const float* __restrict__ B1,
    float* __restrict__ L1R, int i)
{
    __shared__ float eL[3][256];
    const int tx = threadIdx.x;

    // ---- phase A: conv9(i-1) ----
    {
        const int col = tx;
        const bool mL = (col > 0), mR = (col < 255);
        float a0 = 0.f, a1 = 0.f, a2 = 0.f;
        #pragma unroll 4
        for (int cin = 0; cin < 64; ++cin) {
            const float* r_ = L8b + cin * 256;
            float vm = mL ? r_[col - 1] : 0.f;
            float v0 = r_[col];
            float vp = mR ? r_[col + 1] : 0.f;
            const float* wk0 = w9 + (0 * 64 + cin) * 9 + 3;
            const float* wk1 = w9 + (1 * 64 + cin) * 9 + 3;
            const float* wk2 = w9 + (2 * 64 + cin) * 9 + 3;
            a0 += vm * wk0[0] + v0 * wk0[1] + vp * wk0[2];
            a1 += vm * wk1[0] + v0 * wk1[1] + vp * wk1[2];
            a2 += vm * wk2[0] + v0 * wk2[1] + vp * wk2[2];
        }
        const float pv[3] = {LEAKY(b9[0] + a0), LEAKY(b9[1] + a1), LEAKY(b9[2] + a2)};
        #pragma unroll
        for (int j = 0; j < 3; ++j) {
            const float e = x[j * EBCS + (i + 14) * 256 + col] - pv[j];
            eL[j][col] = e;
            if (blockIdx.x == 0) {
                preds[(i - 1) * 768 + j * 256 + col] = pv[j];
                ebuf[j * EBCS + (i + 14) * 256 + col] = e;
            }
        }
    }
    __syncthreads();

    // ---- phase B: conv3inc with eL override ----
    const int lane = tx & 63;
    const int wv   = tx >> 6;
    const int job  = blockIdx.x >> 3;
    const int cq   = blockIdx.x & 3;
    const int z    = (blockIdx.x >> 2) & 1;
    const int cout0 = cq * 16 + wv * 4;
    const float* W  = (z ? W1 : W0) + cout0 * 27;
    const float* Bv = z ? B1 : B0;

    const float* tp[3] = {nullptr, nullptr, nullptr};
    int st[3] = {EBCS, EBCS, EBCS};
    int os;
    if (job == 0) {
        tp[1] = ebuf + i * 256;        tp[2] = ebuf + (i + 1) * 256;
        os = TSL;
    } else if (job == 1) {
        tp[0] = ebuf + (i + 13) * 256; tp[1] = &eL[0][0]; st[1] = 256;
        os = BSL;
    } else {
        tp[0] = ebuf + (i + 12) * 256; tp[1] = ebuf + (i + 13) * 256;
        tp[2] = &eL[0][0]; st[2] = 256;
        os = S16(i + 13);
    }

    float a[4][4] = {};
    #pragma unroll
    for (int t = 0; t < 3; ++t) {
        const float* rp = tp[t];
        if (rp) {
            #pragma unroll
            for (int c = 0; c < 3; ++c) {
                float4 v = *(const float4*)(rp + c * st[t] + lane * 4);
                float wl = __shfl_up(v.w, 1);   if (lane == 0)  wl = 0.f;
                float wr = __shfl_down(v.x, 1); if (lane == 63) wr = 0.f;
                const float win[6] = {wl, v.x, v.y, v.z, v.w, wr};
                #pragma unroll
                for (int j = 0; j < 4; ++j) {
                    const float* wj = W + j * 27 + c * 9 + t * 3;
                    #pragma unroll
                    for (int cc = 0; cc < 4; ++cc)
                        a[j][cc] += wj[0] * win[cc] + wj[1] * win[cc + 1] + wj[2] * win[cc + 2];
                }
            }
        }
    }
    float* o = L1R + (size_t)z * ZS1 + os * 256;
    #pragma unroll
    for (int j = 0; j < 4; ++j) {
        const float bb = Bv[cout0 + j];
        float4 r4;
        r4.x = LEAKY(a[j][0] + bb); r4.y = LEAKY(a[j][1] + bb);
        r4.z = LEAKY(a[j][2] + bb); r4.w = LEAKY(a[j][3] + bb);
        *(float4*)(o + (cout0 + j) * CS + lane * 4) = r4;
    }
}

// ================= fused mm + L5 =================
// grid 192 blocks of (64,4): cout = b&63, jt = b>>6 (0=T,1=B,2=full).
// Fresh mm rows recomputed into rowbuf (each wave its own 16-ch slice); old
// taps read MMR ring. jt=2/cout=0 persists full(i+10) to MMR for future steps.
__global__ __launch_bounds__(256, 2) void fusedL5(
    const float* __restrict__ L4R, float* __restrict__ MMR,
    const float* __restrict__ W, const float* __restrict__ B,
    float* __restrict__ L5R, int i)
{
    __shared__ float rowbuf[64 * 256];   // 64 KB
    __shared__ float red[4][256];
    const int lane = threadIdx.x, y = threadIdx.y;
    const int cout = blockIdx.x & 63, jt = blockIdx.x >> 6;
    const float* Wc = W + cout * 576 + y * 144;

    // tap spec: kind 1 = fresh (slot = L4R source slot), 0 = old (slot = MMR slot)
    int kind[3], slot[3], os;
    if (jt == 0) {
        kind[0] = 1; slot[0] = TSL;
        kind[1] = 0; slot[1] = S16(i + 4);
        kind[2] = 0; slot[2] = S16(i + 5);
        os = TSL;
    } else if (jt == 1) {
        kind[0] = 0; slot[0] = S16(i + 9);
        kind[1] = 1; slot[1] = S16(i + 10);
        kind[2] = 1; slot[2] = BSL;
        os = BSL;
    } else {
        kind[0] = 0; slot[0] = S16(i + 8);
        kind[1] = 0; slot[1] = S16(i + 9);
        kind[2] = 1; slot[2] = S16(i + 10);
        os = S16(i + 9);
    }

    float acc[4] = {};
    #pragma unroll
    for (int t = 0; t < 3; ++t) {
        const float* base;
        int str;
        if (kind[t] == 0) {
            base = MMR + slot[t] * 256;
            str = CS;
        } else {
            // recompute mm row from L4R slot[t]: y does channels [16y,16y+16)
            const float* sB = L4R + slot[t] * 256;          // tower 0 (s)
            const float* eB = L4R + ZS1 + slot[t] * 256;    // tower 1 (e)
            #pragma unroll
            for (int h = 0; h < 2; ++h) {
                const int i8 = y * 2 + h;
                float4 e4[8];
                #pragma unroll
                for (int j = 0; j < 8; ++j)
                    e4[j] = *(const float4*)(eB + (i8 * 8 + j) * CS + lane * 4);
                #pragma unroll
                for (int k = 0; k < 8; ++k) {
                    float4 o4 = {0.f, 0.f, 0.f, 0.f};
                    #pragma unroll
                    for (int j = 0; j < 8; ++j) {
                        float4 s4 = *(const float4*)(sB + (j * 8 + k) * CS + lane * 4);
                        o4.x += e4[j].x * s4.x; o4.y += e4[j].y * s4.y;
                        o4.z += e4[j].z * s4.z; o4.w += e4[j].w * s4.w;
                    }
                    *(float4*)&rowbuf[(i8 * 8 + k) * 256 + lane * 4] = o4;
                }
            }
            if (jt == 2 && cout == 0) {   // persist full(i+10) for future steps
                #pragma unroll
                for (int c = 0; c < 16; ++c) {
                    const int ch = y * 16 + c;
                    *(float4*)(MMR + ch * CS + S16(i + 10) * 256 + lane * 4) =
                        *(const float4*)&rowbuf[ch * 256 + lane * 4];
                }
            }
            base = rowbuf;
            str = 256;
        }
        // accumulate tap t (y reads its own 16-channel slice)
        #pragma unroll 4
        for (int c = 0; c < 16; ++c) {
            const float* rp = base + (y * 16 + c) * str + lane * 4;
            float4 v = *(const float4*)rp;
            float wl = __shfl_up(v.w, 1);   if (lane == 0)  wl = 0.f;
            float wr = __shfl_down(v.x, 1); if (lane == 63) wr = 0.f;
            const float win[6] = {wl, v.x, v.y, v.z, v.w, wr};
            const float* wj = Wc + c * 9 + t * 3;
            #pragma unroll
            for (int cc = 0; cc < 4; ++cc)
                acc[cc] += wj[0] * win[cc] + wj[1] * win[cc + 1] + wj[2] * win[cc + 2];
        }
    }

    *(float4*)&red[y][lane * 4] = *(float4*)acc;
    __syncthreads();
    const int col = y * 64 + lane;
    float v = B[cout] + red[0][col] + red[1][col] + red[2][col] + red[3][col];
    L5R[cout * CS + os * 256 + col] = LEAKY(v);
}

// ================= bootstrap kernels (round 14, verbatim) =================
__global__ __launch_bounds__(256, 2) void conv3B(
    const float* __restrict__ ebuf,
    const float* __restrict__ W0, const float* __restrict__ B0,
    const float* __restrict__ W1, const float* __restrict__ B1,
    float* __restrict__ out)
{
    const int lane = threadIdx.x & 63;
    const int wv   = threadIdx.x >> 6;
    const int h  = blockIdx.y;
    const int cq = blockIdx.z & 3;
    const int z  = blockIdx.z >> 2;
    const int cout0 = cq * 16 + wv * 4;
    const float* W  = (z ? W1 : W0) + cout0 * 27;
    const float* Bv = z ? B1 : B0;

    float a[4][4] = {};
    #pragma unroll
    for (int kh = 0; kh < 3; ++kh) {
        const int r = h - 1 + kh;
        const bool valid = (r >= 0 && r < 15);
        const float msk = valid ? 1.f : 0.f;
        #pragma unroll
        for (int c = 0; c < 3; ++c) {
            const float* rr = ebuf + c * EBCS + (valid ? r : 0) * 256 + lane * 4;
            float4 v = *(const float4*)rr;
            v.x *= msk; v.y *= msk; v.z *= msk; v.w *= msk;
            float wl = __shfl_up(v.w, 1);   if (lane == 0)  wl = 0.f;
            float wr = __shfl_down(v.x, 1); if (lane == 63) wr = 0.f;
            const float win[6] = {wl, v.x, v.y, v.z, v.w, wr};
            #pragma unroll
            for (int j = 0; j < 4; ++j) {
                const float* wj = W + j * 27 + c * 9 + kh * 3;
                #pragma unroll
                for (int cc = 0; cc < 4; ++cc)
                    a[j][cc] += wj[0] * win[cc] + wj[1] * win[cc + 1] + wj[2] * win[cc + 2];
            }
        }
    }
    const int slot = (h == 0) ? TSL : (h == 14 ? BSL : (h & 15));
    float* o = out + (size_t)z * ZS1 + slot * 256;
    #pragma unroll
    for (int j = 0; j < 4; ++j) {
        const float bb = Bv[cout0 + j];
        float4 r4;
        r4.x = LEAKY(a[j][0] + bb); r4.y = LEAKY(a[j][1] + bb);
        r4.z = LEAKY(a[j][2] + bb); r4.w = LEAKY(a[j][3] + bb);
        *(float4*)(o + (cout0 + j) * CS + lane * 4) = r4;
    }
}

template<int HOUT, int HIN, int OFFI, int OFFO, int NZ>
__global__ __launch_bounds__(256, 2) void convYB(
    const float* __restrict__ in,
    const float* __restrict__ W0, const float* __restrict__ B0,
    const float* __restrict__ W1, const float* __restrict__ B1,
    float* __restrict__ out)
{
    const int lane = threadIdx.x;
    const int y    = threadIdx.y;
    const int h  = blockIdx.y;
    const int gz = blockIdx.z;
    const int z    = (NZ == 2) ? (gz >> 6) : 0;
    const int cout = (NZ == 2) ? (gz & 63) : gz;
    const float* W  = (z ? W1 : W0) + cout * 576 + y * 144;
    const float* Bv = z ? B1 : B0;
    const float* ib = in + (size_t)z * ZS1 + y * 16 * CS + lane * 4;

    int slot[3];
    #pragma unroll
    for (int t = 0; t < 3; ++t) {
        const int g = h + t;
        slot[t] = (g == 0) ? TSL : (g == HIN - 1 ? BSL : ((g + OFFI) & 15));
    }

    float acc[4] = {};
    #pragma unroll 4
    for (int c = 0; c < 16; ++c) {
        #pragma unroll
        for (int t = 0; t < 3; ++t) {
            float4 v = *(const float4*)(ib + c * CS + slot[t] * 256);
            float wl = __shfl_up(v.w, 1);   if (lane == 0)  wl = 0.f;
            float wr = __shfl_down(v.x, 1); if (lane == 63) wr = 0.f;
            const float win[6] = {wl, v.x, v.y, v.z, v.w, wr};
            const float* wj = W + c * 9 + t * 3;
            #pragma unroll
            for (int cc = 0; cc < 4; ++cc)
                acc[cc] += wj[0] * win[cc] + wj[1] * win[cc + 1] + wj[2] * win[cc + 2];
        }
    }

    __shared__ float red[4][256];
    *(float4*)&red[y][lane * 4] = *(float4*)acc;
    __syncthreads();
    const int col = y * 64 + lane;
    const int os = (h == 0) ? TSL : (h == HOUT - 1 ? BSL : ((h + OFFO) & 15));
    float v = Bv[cout] + red[0][col] + red[1][col] + red[2][col] + red[3][col];
    out[(size_t)z * ZS1 + cout * CS + os * 256 + col] = LEAKY(v);
}

__global__ __launch_bounds__(256, 2) void mmB(const float* __restrict__ L4R,
                                              float* __restrict__ MMR)
{
    const int col = threadIdx.x;
    const int r   = blockIdx.x;
    const int ig  = blockIdx.y;
    const int slot = (r == 0) ? TSL : (r == 8 ? BSL : ((r + 3) & 15));
    const float* s = L4R + slot * 256 + col;
    const float* e = L4R + ZS1 + slot * 256 + col;
    float sv[64];
    #pragma unroll
    for (int c = 0; c < 64; ++c) sv[c] = s[c * CS];
    float ev[8];
    #pragma unroll
    for (int j = 0; j < 8; ++j) ev[j] = e[(ig * 8 + j) * CS];
    #pragma unroll
    for (int k = 0; k < 8; ++k) {
        float acc = 0.f;
        #pragma unroll
        for (int j = 0; j < 8; ++j) acc += ev[j] * sv[j * 8 + k];
        MMR[(ig * 8 + k) * CS + slot * 256 + col] = acc;
    }
}

// ================= conv9 (round 14, verbatim) — used only for i=15 =================
__global__ void conv9up(const float* __restrict__ pin, const float* __restrict__ w9,
                        const float* __restrict__ b9, const float* __restrict__ x,
                        float* __restrict__ ebuf, float* __restrict__ preds, int i)
{
    const int wcol = threadIdx.x;
    const int yq   = threadIdx.y;
    const int c0   = yq * 16;
    const bool mL = (wcol > 0), mR = (wcol < 255);
    float a0 = 0.f, a1 = 0.f, a2 = 0.f;

    #pragma unroll 4
    for (int c = 0; c < 16; ++c) {
        const int cin = c0 + c;
        const float* r_ = pin + cin * 256;
        float vm = mL ? r_[wcol - 1] : 0.f;
        float v0 = r_[wcol];
        float vp = mR ? r_[wcol + 1] : 0.f;
        const float* wk0 = w9 + (0 * 64 + cin) * 9 + 3;
        const float* wk1 = w9 + (1 * 64 + cin) * 9 + 3;
        const float* wk2 = w9 + (2 * 64 + cin) * 9 + 3;
        a0 += vm * wk0[0] + v0 * wk0[1] + vp * wk0[2];
        a1 += vm * wk1[0] + v0 * wk1[1] + vp * wk1[2];
        a2 += vm * wk2[0] + v0 * wk2[1] + vp * wk2[2];
    }

    __shared__ float red[4][3][256];
    red[yq][0][wcol] = a0;
    red[yq][1][wcol] = a1;
    red[yq][2][wcol] = a2;
    __syncthreads();

    if (yq == 0) {
        #pragma unroll
        for (int j = 0; j < 3; ++j) {
            float v = b9[j] + red[0][j][wcol] + red[1][j][wcol]
                            + red[2][j][wcol] + red[3][j][wcol];
            v = LEAKY(v);
            preds[i * 768 + j * 256 + wcol] = v;
            ebuf[j * EBCS + (15 + i) * 256 + wcol] =
                x[j * EBCS + (15 + i) * 256 + wcol] - v;
        }
    }
}

// ================= finalize (round 14, verbatim) =================
__global__ void finalize(const float* __restrict__ preds, const float* __restrict__ ebuf,
                         float* __restrict__ o)
{
    const int idx = blockIdx.x * 256 + threadIdx.x;
    if (idx >= 24576) return;
    if (idx < 12288) {
        const int c = idx >> 12;
        const int t = (idx >> 8) & 15;
        const int w = idx & 255;
        o[idx] = preds[t * 768 + c * 256 + w];
    } else {
        const int j = idx - 12288;
        const int c = j >> 12;
        const int t = (j >> 8) & 15;
        const int w = j & 255;
        o[idx] = ebuf[c * EBCS + (15 + t) * 256 + w];
    }
}

extern "C" void kernel_launch(void* const* d_in, const int* in_sizes, int n_in,
                              void* d_out, int out_size, void* d_ws, size_t ws_size,
                              hipStream_t stream)
{
    const float* x   = (const float*)d_in[0];
    const float* w1x = (const float*)d_in[1];  const float* b1x = (const float*)d_in[2];
    const float* w2x = (const float*)d_in[3];  const float* b2x = (const float*)d_in[4];
    const float* w3x = (const float*)d_in[5];  const float* b3x = (const float*)d_in[6];
    const float* w4x = (const float*)d_in[7];  const float* b4x = (const float*)d_in[8];
    const float* w1e = (const float*)d_in[9];  const float* b1e = (const float*)d_in[10];
    const float* w2e = (const float*)d_in[11]; const float* b2e = (const float*)d_in[12];
    const float* w3e = (const float*)d_in[13]; const float* b3e = (const float*)d_in[14];
    const float* w4e = (const float*)d_in[15]; const float* b4e = (const float*)d_in[16];
    const float* w5  = (const float*)d_in[17]; const float* b5  = (const float*)d_in[18];
    const float* w6  = (const float*)d_in[19]; const float* b6  = (const float*)d_in[20];
    const float* w7  = (const float*)d_in[21]; const float* b7  = (const float*)d_in[22];
    const float* w8  = (const float*)d_in[23]; const float* b8  = (const float*)d_in[24];
    const float* w9  = (const float*)d_in[25]; const float* b9  = (const float*)d_in[26];

    float* ws    = (float*)d_ws;
    float* ebuf  = ws;
    float* L1R   = ebuf + 23808;
    float* L2R   = L1R + 589824;
    float* L3R   = L2R + 589824;
    float* L4R   = L3R + 589824;
    float* MMR   = L4R + 589824;
    float* L5R   = MMR + 294912;
    float* L6R   = L5R + 294912;
    float* L7b   = L6R + 294912;
    float* L8b   = L7b + 49152;
    float* preds = L8b + 16384;

    auto S2 = [](int c) { return c & 15; };
    auto r2 = [](float* b, int z, int slot) { return b + (size_t)z * ZS1 + slot * 256; };
    auto r1 = [](float* b, int slot) { return b + slot * 256; };

    hipMemcpyAsync(ebuf, x, 23808 * sizeof(float), hipMemcpyDeviceToDevice, stream);

    const dim3 cb(64, 4);

    // ---- bootstrap (step 0: L1..L6) ----
    conv3B<<<dim3(1, 15, 8), 256, 0, stream>>>(ebuf, w1x, b1x, w1e, b1e, L1R);
    convYB<13, 15, 0, 1, 2><<<dim3(1, 13, 128), cb, 0, stream>>>(L1R, w2x, b2x, w2e, b2e, L2R);
    convYB<11, 13, 1, 2, 2><<<dim3(1, 11, 128), cb, 0, stream>>>(L2R, w3x, b3x, w3e, b3e, L3R);
    convYB<9, 11, 2, 3, 2><<<dim3(1, 9, 128), cb, 0, stream>>>(L3R, w4x, b4x, w4e, b4e, L4R);
    mmB<<<dim3(9, 8), 256, 0, stream>>>(L4R, MMR);
    convYB<7, 9, 3, 4, 1><<<dim3(1, 7, 64), cb, 0, stream>>>(MMR, w5, b5, w5, b5, L5R);
    convYB<5, 7, 4, 5, 1><<<dim3(1, 5, 64), cb, 0, stream>>>(L5R, w6, b6, w6, b6, L6R);

    // ---- step-0 tail: L7(0), L8(0); conv9(0) is fused into fusedL1(1) ----
    {
        const int i = 0;
        IncP p7 = {};
        p7.jd[0] = { r1(L6R, TSL),       r1(L6R, S2(i + 6)), r1(L6R, S2(i + 7)), L7b };
        p7.jd[1] = { r1(L6R, S2(i + 6)), r1(L6R, S2(i + 7)), r1(L6R, S2(i + 8)), L7b + 256 };
        p7.jd[2] = { r1(L6R, S2(i + 7)), r1(L6R, S2(i + 8)), r1(L6R, BSL),       L7b + 512 };
        convInc<<<192, cb, 0, stream>>>(p7, w7, b7, w7, b7, 0, CS, 768);
        IncP p8 = {};
        p8.jd[0] = { L7b, L7b + 256, L7b + 512, L8b };
        convInc<<<64, cb, 0, stream>>>(p8, w8, b8, w8, b8, 0, 768, 256);
    }

    for (int i = 1; i < 16; ++i) {
        // fused conv9(i-1) + L1(i)
        fusedL1<<<24, 256, 0, stream>>>(L8b, w9, b9, x, ebuf, preds,
                                        w1x, b1x, w1e, b1e, L1R, i);

        // L2 (round 14, verbatim)
        IncP p2 = {};
        for (int z = 0; z < 2; ++z) {
            p2.jd[0 * 2 + z] = { r2(L1R, z, TSL),        r2(L1R, z, S2(i + 1)),  r2(L1R, z, S2(i + 2)),  r2(L2R, z, TSL) };
            p2.jd[1 * 2 + z] = { r2(L1R, z, S2(i + 12)), r2(L1R, z, S2(i + 13)), r2(L1R, z, BSL),        r2(L2R, z, BSL) };
            p2.jd[2 * 2 + z] = { r2(L1R, z, S2(i + 11)), r2(L1R, z, S2(i + 12)), r2(L1R, z, S2(i + 13)), r2(L2R, z, S2(i + 12)) };
        }
        convInc<<<384, cb, 0, stream>>>(p2, w2x, b2x, w2e, b2e, 42, CS, CS);

        // L3 (verbatim)
        IncP p3i = {};
        for (int z = 0; z < 2; ++z) {
            p3i.jd[0 * 2 + z] = { r2(L2R, z, TSL),        r2(L2R, z, S2(i + 2)),  r2(L2R, z, S2(i + 3)),  r2(L3R, z, TSL) };
            p3i.jd[1 * 2 + z] = { r2(L2R, z, S2(i + 11)), r2(L2R, z, S2(i + 12)), r2(L2R, z, BSL),        r2(L3R, z, BSL) };
            p3i.jd[2 * 2 + z] = { r2(L2R, z, S2(i + 10)), r2(L2R, z, S2(i + 11)), r2(L2R, z, S2(i + 12)), r2(L3R, z, S2(i + 11)) };
        }
        convInc<<<384, cb, 0, stream>>>(p3i, w3x, b3x, w3e, b3e, 42, CS, CS);

        // L4 (verbatim)
        IncP p4 = {};
        for (int z = 0; z < 2; ++z) {
            p4.jd[0 * 2 + z] = { r2(L3R, z, TSL),        r2(L3R, z, S2(i + 3)),  r2(L3R, z, S2(i + 4)),  r2(L4R, z, TSL) };
            p4.jd[1 * 2 + z] = { r2(L3R, z, S2(i + 10)), r2(L3R, z, S2(i + 11)), r2(L3R, z, BSL),        r2(L4R, z, BSL) };
            p4.jd[2 * 2 + z] = { r2(L3R, z, S2(i + 9)),  r2(L3R, z, S2(i + 10)), r2(L3R, z, S2(i + 11)), r2(L4R, z, S2(i + 10)) };
        }
        convInc<<<384, cb, 0, stream>>>(p4, w4x, b4x, w4e, b4e, 42, CS, CS);

        // fused mm + L5
        fusedL5<<<192, cb, 0, stream>>>(L4R, MMR, w5, b5, L5R, i);

        // L6 (verbatim, with the round-15 T-fix)
        IncP p6 = {};
        p6.jd[0] = { r1(L5R, TSL),       r1(L5R, S2(i + 5)), r1(L5R, S2(i + 6)), r1(L6R, TSL) };
        p6.jd[1] = { r1(L5R, S2(i + 8)), r1(L5R, S2(i + 9)), r1(L5R, BSL),       r1(L6R, BSL) };
        p6.jd[2] = { r1(L5R, S2(i + 7)), r1(L5R, S2(i + 8)), r1(L5R, S2(i + 9)), r1(L6R, S2(i + 8)) };
        convInc<<<192, cb, 0, stream>>>(p6, w6, b6, w6, b6, 0, CS, CS);

        // L7 (verbatim)
        IncP p7 = {};
        p7.jd[0] = { r1(L6R, TSL),       r1(L6R, S2(i + 6)), r1(L6R, S2(i + 7)), L7b };
        p7.jd[1] = { r1(L6R, S2(i + 6)), r1(L6R, S2(i + 7)), r1(L6R, S2(i + 8)), L7b + 256 };
        p7.jd[2] = { r1(L6R, S2(i + 7)), r1(L6R, S2(i + 8)), r1(L6R, BSL),       L7b + 512 };
        convInc<<<192, cb, 0, stream>>>(p7, w7, b7, w7, b7, 0, CS, 768);

        // L8 (verbatim)
        IncP p8 = {};
        p8.jd[0] = { L7b, L7b + 256, L7b + 512, L8b };
        convInc<<<64, cb, 0, stream>>>(p8, w8, b8, w8, b8, 0, 768, 256);
    }

    // last step's conv9 (validated kernel) + finalize
    conv9up<<<dim3(1, 1, 1), dim3(256, 4), 0, stream>>>(L8b, w9, b9, x, ebuf, preds, 15);
    finalize<<<96, 256, 0, stream>>>(preds, ebuf, (float*)d_out);
}

// Round 19
// 2719.547 us; speedup vs baseline: 1.4368x; 1.0019x over previous
//
#include <hip/hip_runtime.h>

#define LEAKY(v) ((v) >= 0.f ? (v) : 0.01f * (v))

#define CS   4608      // ring channel stride in floats (18 rows * 256)
#define ZS1  294912    // ring tower stride (64 * CS)
#define TSL  16        // top-pad slot
#define BSL  17        // bottom-pad slot
#define EBCS 7936      // ebuf channel stride (31*256)
#define S16(c) ((c) & 15)

// ================= generic incremental CIN=64 conv (round 14, verbatim) =================
struct JobD { const float* t0; const float* t1; const float* t2; float* o; };
struct IncP { JobD jd[6]; };

__global__ __launch_bounds__(256, 2) void convInc(
    IncP P, const float* __restrict__ W0, const float* __restrict__ B0,
    const float* __restrict__ W1, const float* __restrict__ B1,
    int zsel, int ics, int ocs)
{
    const int lane = threadIdx.x;
    const int y    = threadIdx.y;
    const int q    = blockIdx.x >> 6;
    const int cout = blockIdx.x & 63;
    const int z    = (zsel >> q) & 1;
    const float* W  = (z ? W1 : W0) + cout * 576 + y * 144;
    const float* Bv = z ? B1 : B0;
    const JobD jd  = P.jd[q];
    const int yo   = y * 16 * ics + lane * 4;
    const float* t0 = jd.t0 + yo;
    const float* t1 = jd.t1 + yo;
    const float* t2 = jd.t2 + yo;

    float acc[4] = {};
    #pragma unroll 4
    for (int c = 0; c < 16; ++c) {
        #pragma unroll
        for (int t = 0; t < 3; ++t) {
            const float* rp = (t == 0 ? t0 : (t == 1 ? t1 : t2)) + c * ics;
            float4 v = *(const float4*)rp;
            float wl = __shfl_up(v.w, 1);   if (lane == 0)  wl = 0.f;
            float wr = __shfl_down(v.x, 1); if (lane == 63) wr = 0.f;
            const float win[6] = {wl, v.x, v.y, v.z, v.w, wr};
            const float* wj = W + c * 9 + t * 3;
            #pragma unroll
            for (int cc = 0; cc < 4; ++cc)
                acc[cc] += wj[0] * win[cc] + wj[1] * win[cc + 1] + wj[2] * win[cc + 2];
        }
    }

    __shared__ float red[4][256];
    *(float4*)&red[y][lane * 4] = *(float4*)acc;
    __syncthreads();
    const int col = y * 64 + lane;
    float v = Bv[cout] + red[0][col] + red[1][col] + red[2][col] + red[3][col];
    jd.o[cout * ocs + col] = LEAKY(v);
}

// ================= fused conv9(i-1) + L1(i)  (round 18, validated) =================
__global__ __launch_bounds__(256, 2) void fusedL1(
    const float* __restrict__ L8b, const float* __restrict__ w9,
    const float* __restrict__ b9, const float* __restrict__ x,
    float* __restrict__ ebuf, float* __restrict__ preds,
    const float* __restrict__ W0, const float* __restrict__ B0,
    const float* __restrict__ W1, const float* __restrict__ B1,
    float* __restrict__ L1R, int i)
{
    __shared__ float eL[3][256];
    const int tx = threadIdx.x;

    // ---- phase A: conv9(i-1) ----
    {
        const int col = tx;
        const bool mL = (col > 0), mR = (col < 255);
        float a0 = 0.f, a1 = 0.f, a2 = 0.f;
        #pragma unroll 4
        for (int cin = 0; cin < 64; ++cin) {
            const float* r_ = L8b + cin * 256;
            float vm = mL ? r_[col - 1] : 0.f;
            float v0 = r_[col];
            float vp = mR ? r_[col + 1] : 0.f;
            const float* wk0 = w9 + (0 * 64 + cin) * 9 + 3;
            const float* wk1 = w9 + (1 * 64 + cin) * 9 + 3;
            const float* wk2 = w9 + (2 * 64 + cin) * 9 + 3;
            a0 += vm * wk0[0] + v0 * wk0[1] + vp * wk0[2];
            a1 += vm * wk1[0] + v0 * wk1[1] + vp * wk1[2];
            a2 += vm * wk2[0] + v0 * wk2[1] + vp * wk2[2];
        }
        const float pv[3] = {LEAKY(b9[0] + a0), LEAKY(b9[1] + a1), LEAKY(b9[2] + a2)};
        #pragma unroll
        for (int j = 0; j < 3; ++j) {
            const float e = x[j * EBCS + (i + 14) * 256 + col] - pv[j];
            eL[j][col] = e;
            if (blockIdx.x == 0) {
                preds[(i - 1) * 768 + j * 256 + col] = pv[j];
                ebuf[j * EBCS + (i + 14) * 256 + col] = e;
            }
        }
    }
    __syncthreads();

    // ---- phase B: conv3inc with eL override ----
    const int lane = tx & 63;
    const int wv   = tx >> 6;
    const int job  = blockIdx.x >> 3;
    const int cq   = blockIdx.x & 3;
    const int z    = (blockIdx.x >> 2) & 1;
    const int cout0 = cq * 16 + wv * 4;
    const float* W  = (z ? W1 : W0) + cout0 * 27;
    const float* Bv = z ? B1 : B0;

    const float* tp[3] = {nullptr, nullptr, nullptr};
    int st[3] = {EBCS, EBCS, EBCS};
    int os;
    if (job == 0) {
        tp[1] = ebuf + i * 256;        tp[2] = ebuf + (i + 1) * 256;
        os = TSL;
    } else if (job == 1) {
        tp[0] = ebuf + (i + 13) * 256; tp[1] = &eL[0][0]; st[1] = 256;
        os = BSL;
    } else {
        tp[0] = ebuf + (i + 12) * 256; tp[1] = ebuf + (i + 13) * 256;
        tp[2] = &eL[0][0]; st[2] = 256;
        os = S16(i + 13);
    }

    float a[4][4] = {};
    #pragma unroll
    for (int t = 0; t < 3; ++t) {
        const float* rp = tp[t];
        if (rp) {
            #pragma unroll
            for (int c = 0; c < 3; ++c) {
                float4 v = *(const float4*)(rp + c * st[t] + lane * 4);
                float wl = __shfl_up(v.w, 1);   if (lane == 0)  wl = 0.f;
                float wr = __shfl_down(v.x, 1); if (lane == 63) wr = 0.f;
                const float win[6] = {wl, v.x, v.y, v.z, v.w, wr};
                #pragma unroll
                for (int j = 0; j < 4; ++j) {
                    const float* wj = W + j * 27 + c * 9 + t * 3;
                    #pragma unroll
                    for (int cc = 0; cc < 4; ++cc)
                        a[j][cc] += wj[0] * win[cc] + wj[1] * win[cc + 1] + wj[2] * win[cc + 2];
                }
            }
        }
    }
    float* o = L1R + (size_t)z * ZS1 + os * 256;
    #pragma unroll
    for (int j = 0; j < 4; ++j) {
        const float bb = Bv[cout0 + j];
        float4 r4;
        r4.x = LEAKY(a[j][0] + bb); r4.y = LEAKY(a[j][1] + bb);
        r4.z = LEAKY(a[j][2] + bb); r4.w = LEAKY(a[j][3] + bb);
        *(float4*)(o + (cout0 + j) * CS + lane * 4) = r4;
    }
}

// ================= fused mm + L5, register-space (lean rewrite) =================
// grid 192 blocks of (64,4): cout = b&63, jt = b>>6 (0=T,1=B,2=full).
// Fresh mm channels computed per-wave (own 16-ch slice) straight into the
// conv-tap accumulation; no rowbuf. Same FP order as round 18 -> bit-identical.
__global__ __launch_bounds__(256, 2) void fusedL5(
    const float* __restrict__ L4R, float* __restrict__ MMR,
    const float* __restrict__ W, const float* __restrict__ B,
    float* __restrict__ L5R, int i)
{
    __shared__ float red[4][256];
    const int lane = threadIdx.x, y = threadIdx.y;
    const int cout = blockIdx.x & 63, jt = blockIdx.x >> 6;
    const float* Wc = W + cout * 576 + y * 144;

#define CONV_ACC(v, c, t) do {                                                 \
        float wl_ = __shfl_up((v).w, 1);   if (lane == 0)  wl_ = 0.f;          \
        float wr_ = __shfl_down((v).x, 1); if (lane == 63) wr_ = 0.f;          \
        const float win_[6] = {wl_, (v).x, (v).y, (v).z, (v).w, wr_};          \
        const float* wj_ = Wc + (c) * 9 + (t) * 3;                             \
        _Pragma("unroll")                                                      \
        for (int cc = 0; cc < 4; ++cc)                                         \
            acc[cc] += wj_[0] * win_[cc] + wj_[1] * win_[cc + 1]               \
                     + wj_[2] * win_[cc + 2];                                  \
    } while (0)

    // tap spec: kind 1 = fresh (slot = L4R source slot), 0 = old (slot = MMR slot)
    int kind[3], slot[3], os;
    if (jt == 0) {
        kind[0] = 1; slot[0] = TSL;
        kind[1] = 0; slot[1] = S16(i + 4);
        kind[2] = 0; slot[2] = S16(i + 5);
        os = TSL;
    } else if (jt == 1) {
        kind[0] = 0; slot[0] = S16(i + 9);
        kind[1] = 1; slot[1] = S16(i + 10);
        kind[2] = 1; slot[2] = BSL;
        os = BSL;
    } else {
        kind[0] = 0; slot[0] = S16(i + 8);
        kind[1] = 0; slot[1] = S16(i + 9);
        kind[2] = 1; slot[2] = S16(i + 10);
        os = S16(i + 9);
    }

    float acc[4] = {};
    #pragma unroll
    for (int t = 0; t < 3; ++t) {
        if (kind[t] == 0) {
            const float* base = MMR + slot[t] * 256 + y * 16 * CS + lane * 4;
            #pragma unroll 4
            for (int c = 0; c < 16; ++c) {
                float4 v = *(const float4*)(base + c * CS);
                CONV_ACC(v, c, t);
            }
        } else {
            const float* sB = L4R + slot[t] * 256 + lane * 4;          // tower 0 (s)
            const float* eB = L4R + ZS1 + slot[t] * 256 + lane * 4;    // tower 1 (e)
            const bool persist = (jt == 2) && (cout == 0) && (t == 2);
            #pragma unroll
            for (int h = 0; h < 2; ++h) {
                const int i8 = y * 2 + h;
                float4 e4[8];
                #pragma unroll
                for (int j = 0; j < 8; ++j)
                    e4[j] = *(const float4*)(eB + (i8 * 8 + j) * CS);
                #pragma unroll
                for (int k = 0; k < 8; ++k) {
                    float4 v = {0.f, 0.f, 0.f, 0.f};
                    #pragma unroll
                    for (int j = 0; j < 8; ++j) {
                        float4 s4 = *(const float4*)(sB + (j * 8 + k) * CS);
                        v.x += e4[j].x * s4.x; v.y += e4[j].y * s4.y;
                        v.z += e4[j].z * s4.z; v.w += e4[j].w * s4.w;
                    }
                    if (persist)
                        *(float4*)(MMR + (i8 * 8 + k) * CS + S16(i + 10) * 256 + lane * 4) = v;
                    CONV_ACC(v, h * 8 + k, t);
                }
            }
        }
    }
#undef CONV_ACC

    *(float4*)&red[y][lane * 4] = *(float4*)acc;
    __syncthreads();
    const int col = y * 64 + lane;
    float v = B[cout] + red[0][col] + red[1][col] + red[2][col] + red[3][col];
    L5R[cout * CS + os * 256 + col] = LEAKY(v);
}

// ================= bootstrap kernels (round 14, verbatim) =================
__global__ __launch_bounds__(256, 2) void conv3B(
    const float* __restrict__ ebuf,
    const float* __restrict__ W0, const float* __restrict__ B0,
    const float* __restrict__ W1, const float* __restrict__ B1,
    float* __restrict__ out)
{
    const int lane = threadIdx.x & 63;
    const int wv   = threadIdx.x >> 6;
    const int h  = blockIdx.y;
    const int cq = blockIdx.z & 3;
    const int z  = blockIdx.z >> 2;
    const int cout0 = cq * 16 + wv * 4;
    const float* W  = (z ? W1 : W0) + cout0 * 27;
    const float* Bv = z ? B1 : B0;

    float a[4][4] = {};
    #pragma unroll
    for (int kh = 0; kh < 3; ++kh) {
        const int r = h - 1 + kh;
        const bool valid = (r >= 0 && r < 15);
        const float msk = valid ? 1.f : 0.f;
        #pragma unroll
        for (int c = 0; c < 3; ++c) {
            const float* rr = ebuf + c * EBCS + (valid ? r : 0) * 256 + lane * 4;
            float4 v = *(const float4*)rr;
            v.x *= msk; v.y *= msk; v.z *= msk; v.w *= msk;
            float wl = __shfl_up(v.w, 1);   if (lane == 0)  wl = 0.f;
            float wr = __shfl_down(v.x, 1); if (lane == 63) wr = 0.f;
            const float win[6] = {wl, v.x, v.y, v.z, v.w, wr};
            #pragma unroll
            for (int j = 0; j < 4; ++j) {
                const float* wj = W + j * 27 + c * 9 + kh * 3;
                #pragma unroll
                for (int cc = 0; cc < 4; ++cc)
                    a[j][cc] += wj[0] * win[cc] + wj[1] * win[cc + 1] + wj[2] * win[cc + 2];
            }
        }
    }
    const int slot = (h == 0) ? TSL : (h == 14 ? BSL : (h & 15));
    float* o = out + (size_t)z * ZS1 + slot * 256;
    #pragma unroll
    for (int j = 0; j < 4; ++j) {
        const float bb = Bv[cout0 + j];
        float4 r4;
        r4.x = LEAKY(a[j][0] + bb); r4.y = LEAKY(a[j][1] + bb);
        r4.z = LEAKY(a[j][2] + bb); r4.w = LEAKY(a[j][3] + bb);
        *(float4*)(o + (cout0 + j) * CS + lane * 4) = r4;
    }
}

template<int HOUT, int HIN, int OFFI, int OFFO, int NZ>
__global__ __launch_bounds__(256, 2) void convYB(
    const float* __restrict__ in,
    const float* __restrict__ W0, const float* __restrict__ B0,
    const float* __restrict__ W1, const float* __restrict__ B1,
    float* __restrict__ out)
{
    const int lane = threadIdx.x;
    const int y    = threadIdx.y;
    const int h  = blockIdx.y;
    const int gz = blockIdx.z;
    const int z    = (NZ == 2) ? (gz >> 6) : 0;
    const int cout = (NZ == 2) ? (gz & 63) : gz;
    const float* W  = (z ? W1 : W0) + cout * 576 + y * 144;
    const float* Bv = z ? B1 : B0;
    const float* ib = in + (size_t)z * ZS1 + y * 16 * CS + lane * 4;

    int slot[3];
    #pragma unroll
    for (int t = 0; t < 3; ++t) {
        const int g = h + t;
        slot[t] = (g == 0) ? TSL : (g == HIN - 1 ? BSL : ((g + OFFI) & 15));
    }

    float acc[4] = {};
    #pragma unroll 4
    for (int c = 0; c < 16; ++c) {
        #pragma unroll
        for (int t = 0; t < 3; ++t) {
            float4 v = *(const float4*)(ib + c * CS + slot[t] * 256);
            float wl = __shfl_up(v.w, 1);   if (lane == 0)  wl = 0.f;
            float wr = __shfl_down(v.x, 1); if (lane == 63) wr = 0.f;
            const float win[6] = {wl, v.x, v.y, v.z, v.w, wr};
            const float* wj = W + c * 9 + t * 3;
            #pragma unroll
            for (int cc = 0; cc < 4; ++cc)
                acc[cc] += wj[0] * win[cc] + wj[1] * win[cc + 1] + wj[2] * win[cc + 2];
        }
    }

    __shared__ float red[4][256];
    *(float4*)&red[y][lane * 4] = *(float4*)acc;
    __syncthreads();
    const int col = y * 64 + lane;
    const int os = (h == 0) ? TSL : (h == HOUT - 1 ? BSL : ((h + OFFO) & 15));
    float v = Bv[cout] + red[0][col] + red[1][col] + red[2][col] + red[3][col];
    out[(size_t)z * ZS1 + cout * CS + os * 256 + col] = LEAKY(v);
}

__global__ __launch_bounds__(256, 2) void mmB(const float* __restrict__ L4R,
                                              float* __restrict__ MMR)
{
    const int col = threadIdx.x;
    const int r   = blockIdx.x;
    const int ig  = blockIdx.y;
    const int slot = (r == 0) ? TSL : (r == 8 ? BSL : ((r + 3) & 15));
    const float* s = L4R + slot * 256 + col;
    const float* e = L4R + ZS1 + slot * 256 + col;
    float sv[64];
    #pragma unroll
    for (int c = 0; c < 64; ++c) sv[c] = s[c * CS];
    float ev[8];
    #pragma unroll
    for (int j = 0; j < 8; ++j) ev[j] = e[(ig * 8 + j) * CS];
    #pragma unroll
    for (int k = 0; k < 8; ++k) {
        float acc = 0.f;
        #pragma unroll
        for (int j = 0; j < 8; ++j) acc += ev[j] * sv[j * 8 + k];
        MMR[(ig * 8 + k) * CS + slot * 256 + col] = acc;
    }
}

// ================= conv9 (round 14, verbatim) — used only for i=15 =================
__global__ void conv9up(const float* __restrict__ pin, const float* __restrict__ w9,
                        const float* __restrict__ b9, const float* __restrict__ x,
                        float* __restrict__ ebuf, float* __restrict__ preds, int i)
{
    const int wcol = threadIdx.x;
    const int yq   = threadIdx.y;
    const int c0   = yq * 16;
    const bool mL = (wcol > 0), mR = (wcol < 255);
    float a0 = 0.f, a1 = 0.f, a2 = 0.f;

    #pragma unroll 4
    for (int c = 0; c < 16; ++c) {
        const int cin = c0 + c;
        const float* r_ = pin + cin * 256;
        float vm = mL ? r_[wcol - 1] : 0.f;
        float v0 = r_[wcol];
        float vp = mR ? r_[wcol + 1] : 0.f;
        const float* wk0 = w9 + (0 * 64 + cin) * 9 + 3;
        const float* wk1 = w9 + (1 * 64 + cin) * 9 + 3;
        const float* wk2 = w9 + (2 * 64 + cin) * 9 + 3;
        a0 += vm * wk0[0] + v0 * wk0[1] + vp * wk0[2];
        a1 += vm * wk1[0] + v0 * wk1[1] + vp * wk1[2];
        a2 += vm * wk2[0] + v0 * wk2[1] + vp * wk2[2];
    }

    __shared__ float red[4][3][256];
    red[yq][0][wcol] = a0;
    red[yq][1][wcol] = a1;
    red[yq][2][wcol] = a2;
    __syncthreads();

    if (yq == 0) {
        #pragma unroll
        for (int j = 0; j < 3; ++j) {
            float v = b9[j] + red[0][j][wcol] + red[1][j][wcol]
                            + red[2][j][wcol] + red[3][j][wcol];
            v = LEAKY(v);
            preds[i * 768 + j * 256 + wcol] = v;
            ebuf[j * EBCS + (15 + i) * 256 + wcol] =
                x[j * EBCS + (15 + i) * 256 + wcol] - v;
        }
    }
}

// ================= finalize (round 14, verbatim) =================
__global__ void finalize(const float* __restrict__ preds, const float* __restrict__ ebuf,
                         float* __restrict__ o)
{
    const int idx = blockIdx.x * 256 + threadIdx.x;
    if (idx >= 24576) return;
    if (idx < 12288) {
        const int c = idx >> 12;
        const int t = (idx >> 8) & 15;
        const int w = idx & 255;
        o[idx] = preds[t * 768 + c * 256 + w];
    } else {
        const int j = idx - 12288;
        const int c = j >> 12;
        const int t = (j >> 8) & 15;
        const int w = j & 255;
        o[idx] = ebuf[c * EBCS + (15 + t) * 256 + w];
    }
}

extern "C" void kernel_launch(void* const* d_in, const int* in_sizes, int n_in,
                              void* d_out, int out_size, void* d_ws, size_t ws_size,
                              hipStream_t stream)
{
    const float* x   = (const float*)d_in[0];
    const float* w1x = (const float*)d_in[1];  const float* b1x = (const float*)d_in[2];
    const float* w2x = (const float*)d_in[3];  const float* b2x = (const float*)d_in[4];
    const float* w3x = (const float*)d_in[5];  const float* b3x = (const float*)d_in[6];
    const float* w4x = (const float*)d_in[7];  const float* b4x = (const float*)d_in[8];
    const float* w1e = (const float*)d_in[9];  const float* b1e = (const float*)d_in[10];
    const float* w2e = (const float*)d_in[11]; const float* b2e = (const float*)d_in[12];
    const float* w3e = (const float*)d_in[13]; const float* b3e = (const float*)d_in[14];
    const float* w4e = (const float*)d_in[15]; const float* b4e = (const float*)d_in[16];
    const float* w5  = (const float*)d_in[17]; const float* b5  = (const float*)d_in[18];
    const float* w6  = (const float*)d_in[19]; const float* b6  = (const float*)d_in[20];
    const float* w7  = (const float*)d_in[21]; const float* b7  = (const float*)d_in[22];
    const float* w8  = (const float*)d_in[23]; const float* b8  = (const float*)d_in[24];
    const float* w9  = (const float*)d_in[25]; const float* b9  = (const float*)d_in[26];

    float* ws    = (float*)d_ws;
    float* ebuf  = ws;
    float* L1R   = ebuf + 23808;
    float* L2R   = L1R + 589824;
    float* L3R   = L2R + 589824;
    float* L4R   = L3R + 589824;
    float* MMR   = L4R + 589824;
    float* L5R   = MMR + 294912;
    float* L6R   = L5R + 294912;
    float* L7b   = L6R + 294912;
    float* L8b   = L7b + 49152;
    float* preds = L8b + 16384;

    auto S2 = [](int c) { return c & 15; };
    auto r2 = [](float* b, int z, int slot) { return b + (size_t)z * ZS1 + slot * 256; };
    auto r1 = [](float* b, int slot) { return b + slot * 256; };

    hipMemcpyAsync(ebuf, x, 23808 * sizeof(float), hipMemcpyDeviceToDevice, stream);

    const dim3 cb(64, 4);

    // ---- bootstrap (step 0: L1..L6) ----
    conv3B<<<dim3(1, 15, 8), 256, 0, stream>>>(ebuf, w1x, b1x, w1e, b1e, L1R);
    convYB<13, 15, 0, 1, 2><<<dim3(1, 13, 128), cb, 0, stream>>>(L1R, w2x, b2x, w2e, b2e, L2R);
    convYB<11, 13, 1, 2, 2><<<dim3(1, 11, 128), cb, 0, stream>>>(L2R, w3x, b3x, w3e, b3e, L3R);
    convYB<9, 11, 2, 3, 2><<<dim3(1, 9, 128), cb, 0, stream>>>(L3R, w4x, b4x, w4e, b4e, L4R);
    mmB<<<dim3(9, 8), 256, 0, stream>>>(L4R, MMR);
    convYB<7, 9, 3, 4, 1><<<dim3(1, 7, 64), cb, 0, stream>>>(MMR, w5, b5, w5, b5, L5R);
    convYB<5, 7, 4, 5, 1><<<dim3(1, 5, 64), cb, 0, stream>>>(L5R, w6, b6, w6, b6, L6R);

    // ---- step-0 tail: L7(0), L8(0); conv9(0) fused into fusedL1(1) ----
    {
        const int i = 0;
        IncP p7 = {};
        p7.jd[0] = { r1(L6R, TSL),       r1(L6R, S2(i + 6)), r1(L6R, S2(i + 7)), L7b };
        p7.jd[1] = { r1(L6R, S2(i + 6)), r1(L6R, S2(i + 7)), r1(L6R, S2(i + 8)), L7b + 256 };
        p7.jd[2] = { r1(L6R, S2(i + 7)), r1(L6R, S2(i + 8)), r1(L6R, BSL),       L7b + 512 };
        convInc<<<192, cb, 0, stream>>>(p7, w7, b7, w7, b7, 0, CS, 768);
        IncP p8 = {};
        p8.jd[0] = { L7b, L7b + 256, L7b + 512, L8b };
        convInc<<<64, cb, 0, stream>>>(p8, w8, b8, w8, b8, 0, 768, 256);
    }

    for (int i = 1; i < 16; ++i) {
        fusedL1<<<24, 256, 0, stream>>>(L8b, w9, b9, x, ebuf, preds,
                                        w1x, b1x, w1e, b1e, L1R, i);

        IncP p2 = {};
        for (int z = 0; z < 2; ++z) {
            p2.jd[0 * 2 + z] = { r2(L1R, z, TSL),        r2(L1R, z, S2(i + 1)),  r2(L1R, z, S2(i + 2)),  r2(L2R, z, TSL) };
            p2.jd[1 * 2 + z] = { r2(L1R, z, S2(i + 12)), r2(L1R, z, S2(i + 13)), r2(L1R, z, BSL),        r2(L2R, z, BSL) };
            p2.jd[2 * 2 + z] = { r2(L1R, z, S2(i + 11)), r2(L1R, z, S2(i + 12)), r2(L1R, z, S2(i + 13)), r2(L2R, z, S2(i + 12)) };
        }
        convInc<<<384, cb, 0, stream>>>(p2, w2x, b2x, w2e, b2e, 42, CS, CS);

        IncP p3i = {};
        for (int z = 0; z < 2; ++z) {
            p3i.jd[0 * 2 + z] = { r2(L2R, z, TSL),        r2(L2R, z, S2(i + 2)),  r2(L2R, z, S2(i + 3)),  r2(L3R, z, TSL) };
            p3i.jd[1 * 2 + z] = { r2(L2R, z, S2(i + 11)), r2(L2R, z, S2(i + 12)), r2(L2R, z, BSL),        r2(L3R, z, BSL) };
            p3i.jd[2 * 2 + z] = { r2(L2R, z, S2(i + 10)), r2(L2R, z, S2(i + 11)), r2(L2R, z, S2(i + 12)), r2(L3R, z, S2(i + 11)) };
        }
        convInc<<<384, cb, 0, stream>>>(p3i, w3x, b3x, w3e, b3e, 42, CS, CS);

        IncP p4 = {};
        for (int z = 0; z < 2; ++z) {
            p4.jd[0 * 2 + z] = { r2(L3R, z, TSL),        r2(L3R, z, S2(i + 3)),  r2(L3R, z, S2(i + 4)),  r2(L4R, z, TSL) };
            p4.jd[1 * 2 + z] = { r2(L3R, z, S2(i + 10)), r2(L3R, z, S2(i + 11)), r2(L3R, z, BSL),        r2(L4R, z, BSL) };
            p4.jd[2 * 2 + z] = { r2(L3R, z, S2(i + 9)),  r2(L3R, z, S2(i + 10)), r2(L3R, z, S2(i + 11)), r2(L4R, z, S2(i + 10)) };
        }
        convInc<<<384, cb, 0, stream>>>(p4, w4x, b4x, w4e, b4e, 42, CS, CS);

        fusedL5<<<192, cb, 0, stream>>>(L4R, MMR, w5, b5, L5R, i);

        IncP p6 = {};
        p6.jd[0] = { r1(L5R, TSL),       r1(L5R, S2(i + 5)), r1(L5R, S2(i + 6)), r1(L6R, TSL) };
        p6.jd[1] = { r1(L5R, S2(i + 8)), r1(L5R, S2(i + 9)), r1(L5R, BSL),       r1(L6R, BSL) };
        p6.jd[2] = { r1(L5R, S2(i + 7)), r1(L5R, S2(i + 8)), r1(L5R, S2(i + 9)), r1(L6R, S2(i + 8)) };
        convInc<<<192, cb, 0, stream>>>(p6, w6, b6, w6, b6, 0, CS, CS);

        IncP p7 = {};
        p7.jd[0] = { r1(L6R, TSL),       r1(L6R, S2(i + 6)), r1(L6R, S2(i + 7)), L7b };
        p7.jd[1] = { r1(L6R, S2(i + 6)), r1(L6R, S2(i + 7)), r1(L6R, S2(i + 8)), L7b + 256 };
        p7.jd[2] = { r1(L6R, S2(i + 7)), r1(L6R, S2(i + 8)), r1(L6R, BSL),       L7b + 512 };
        convInc<<<192, cb, 0, stream>>>(p7, w7, b7, w7, b7, 0, CS, 768);

        IncP p8 = {};
        p8.jd[0] = { L7b, L7b + 256, L7b + 512, L8b };
        convInc<<<64, cb, 0, stream>>>(p8, w8, b8, w8, b8, 0, 768, 256);
    }

    conv9up<<<dim3(1, 1, 1), dim3(256, 4), 0, stream>>>(L8b, w9, b9, x, ebuf, preds, 15);
    finalize<<<96, 256, 0, stream>>>(preds, ebuf, (float*)d_out);
}

// Round 20
// 2037.860 us; speedup vs baseline: 1.9175x; 1.3345x over previous
//
#include <hip/hip_runtime.h>

#define LEAKY(v) ((v) >= 0.f ? (v) : 0.01f * (v))

#define CS   4608      // ring channel stride in floats (18 rows * 256)
#define ZS1  294912    // ring tower stride (64 * CS)
#define TSL  16        // top-pad slot
#define BSL  17        // bottom-pad slot
#define EBCS 7936      // ebuf channel stride (31*256)
#define S16(c) ((c) & 15)

// ================= generic incremental CIN=64 conv (round 14, verbatim) =================
struct JobD { const float* t0; const float* t1; const float* t2; float* o; };
struct IncP { JobD jd[6]; };

__global__ __launch_bounds__(256, 2) void convInc(
    IncP P, const float* __restrict__ W0, const float* __restrict__ B0,
    const float* __restrict__ W1, const float* __restrict__ B1,
    int zsel, int ics, int ocs)
{
    const int lane = threadIdx.x;
    const int y    = threadIdx.y;
    const int q    = blockIdx.x >> 6;
    const int cout = blockIdx.x & 63;
    const int z    = (zsel >> q) & 1;
    const float* W  = (z ? W1 : W0) + cout * 576 + y * 144;
    const float* Bv = z ? B1 : B0;
    const JobD jd  = P.jd[q];
    const int yo   = y * 16 * ics + lane * 4;
    const float* t0 = jd.t0 + yo;
    const float* t1 = jd.t1 + yo;
    const float* t2 = jd.t2 + yo;

    float acc[4] = {};
    #pragma unroll 4
    for (int c = 0; c < 16; ++c) {
        #pragma unroll
        for (int t = 0; t < 3; ++t) {
            const float* rp = (t == 0 ? t0 : (t == 1 ? t1 : t2)) + c * ics;
            float4 v = *(const float4*)rp;
            float wl = __shfl_up(v.w, 1);   if (lane == 0)  wl = 0.f;
            float wr = __shfl_down(v.x, 1); if (lane == 63) wr = 0.f;
            const float win[6] = {wl, v.x, v.y, v.z, v.w, wr};
            const float* wj = W + c * 9 + t * 3;
            #pragma unroll
            for (int cc = 0; cc < 4; ++cc)
                acc[cc] += wj[0] * win[cc] + wj[1] * win[cc + 1] + wj[2] * win[cc + 2];
        }
    }

    __shared__ float red[4][256];
    *(float4*)&red[y][lane * 4] = *(float4*)acc;
    __syncthreads();
    const int col = y * 64 + lane;
    float v = Bv[cout] + red[0][col] + red[1][col] + red[2][col] + red[3][col];
    jd.o[cout * ocs + col] = LEAKY(v);
}

// ================= fused conv9(i-1) + L1(i)  (round 18, validated) =================
__global__ __launch_bounds__(256, 2) void fusedL1(
    const float* __restrict__ L8b, const float* __restrict__ w9,
    const float* __restrict__ b9, const float* __restrict__ x,
    float* __restrict__ ebuf, float* __restrict__ preds,
    const float* __restrict__ W0, const float* __restrict__ B0,
    const float* __restrict__ W1, const float* __restrict__ B1,
    float* __restrict__ L1R, int i)
{
    __shared__ float eL[3][256];
    const int tx = threadIdx.x;

    // ---- phase A: conv9(i-1) ----
    {
        const int col = tx;
        const bool mL = (col > 0), mR = (col < 255);
        float a0 = 0.f, a1 = 0.f, a2 = 0.f;
        #pragma unroll 4
        for (int cin = 0; cin < 64; ++cin) {
            const float* r_ = L8b + cin * 256;
            float vm = mL ? r_[col - 1] : 0.f;
            float v0 = r_[col];
            float vp = mR ? r_[col + 1] : 0.f;
            const float* wk0 = w9 + (0 * 64 + cin) * 9 + 3;
            const float* wk1 = w9 + (1 * 64 + cin) * 9 + 3;
            const float* wk2 = w9 + (2 * 64 + cin) * 9 + 3;
            a0 += vm * wk0[0] + v0 * wk0[1] + vp * wk0[2];
            a1 += vm * wk1[0] + v0 * wk1[1] + vp * wk1[2];
            a2 += vm * wk2[0] + v0 * wk2[1] + vp * wk2[2];
        }
        const float pv[3] = {LEAKY(b9[0] + a0), LEAKY(b9[1] + a1), LEAKY(b9[2] + a2)};
        #pragma unroll
        for (int j = 0; j < 3; ++j) {
            const float e = x[j * EBCS + (i + 14) * 256 + col] - pv[j];
            eL[j][col] = e;
            if (blockIdx.x == 0) {
                preds[(i - 1) * 768 + j * 256 + col] = pv[j];
                ebuf[j * EBCS + (i + 14) * 256 + col] = e;
            }
        }
    }
    __syncthreads();

    // ---- phase B: conv3inc with eL override ----
    const int lane = tx & 63;
    const int wv   = tx >> 6;
    const int job  = blockIdx.x >> 3;
    const int cq   = blockIdx.x & 3;
    const int z    = (blockIdx.x >> 2) & 1;
    const int cout0 = cq * 16 + wv * 4;
    const float* W  = (z ? W1 : W0) + cout0 * 27;
    const float* Bv = z ? B1 : B0;

    const float* tp[3] = {nullptr, nullptr, nullptr};
    int st[3] = {EBCS, EBCS, EBCS};
    int os;
    if (job == 0) {
        tp[1] = ebuf + i * 256;        tp[2] = ebuf + (i + 1) * 256;
        os = TSL;
    } else if (job == 1) {
        tp[0] = ebuf + (i + 13) * 256; tp[1] = &eL[0][0]; st[1] = 256;
        os = BSL;
    } else {
        tp[0] = ebuf + (i + 12) * 256; tp[1] = ebuf + (i + 13) * 256;
        tp[2] = &eL[0][0]; st[2] = 256;
        os = S16(i + 13);
    }

    float a[4][4] = {};
    #pragma unroll
    for (int t = 0; t < 3; ++t) {
        const float* rp = tp[t];
        if (rp) {
            #pragma unroll
            for (int c = 0; c < 3; ++c) {
                float4 v = *(const float4*)(rp + c * st[t] + lane * 4);
                float wl = __shfl_up(v.w, 1);   if (lane == 0)  wl = 0.f;
                float wr = __shfl_down(v.x, 1); if (lane == 63) wr = 0.f;
                const float win[6] = {wl, v.x, v.y, v.z, v.w, wr};
                #pragma unroll
                for (int j = 0; j < 4; ++j) {
                    const float* wj = W + j * 27 + c * 9 + t * 3;
                    #pragma unroll
                    for (int cc = 0; cc < 4; ++cc)
                        a[j][cc] += wj[0] * win[cc] + wj[1] * win[cc + 1] + wj[2] * win[cc + 2];
                }
            }
        }
    }
    float* o = L1R + (size_t)z * ZS1 + os * 256;
    #pragma unroll
    for (int j = 0; j < 4; ++j) {
        const float bb = Bv[cout0 + j];
        float4 r4;
        r4.x = LEAKY(a[j][0] + bb); r4.y = LEAKY(a[j][1] + bb);
        r4.z = LEAKY(a[j][2] + bb); r4.w = LEAKY(a[j][3] + bb);
        *(float4*)(o + (cout0 + j) * CS + lane * 4) = r4;
    }
}

// ================= incremental mm (round 14, verbatim) =================
struct MMP { const float* s[3]; const float* e[3]; float* o[3]; };
__global__ __launch_bounds__(256, 2) void mminc(MMP P)
{
    const int col = threadIdx.x;
    const int job = blockIdx.x;
    const int ig  = blockIdx.y;
    const float* s = P.s[job] + col;
    const float* e = P.e[job] + col;
    float sv[64];
    #pragma unroll
    for (int c = 0; c < 64; ++c) sv[c] = s[c * CS];
    float ev[8];
    #pragma unroll
    for (int j = 0; j < 8; ++j) ev[j] = e[(ig * 8 + j) * CS];
    float* o = P.o[job];
    #pragma unroll
    for (int k = 0; k < 8; ++k) {
        float acc = 0.f;
        #pragma unroll
        for (int j = 0; j < 8; ++j) acc += ev[j] * sv[j * 8 + k];
        o[(ig * 8 + k) * CS + col] = acc;
    }
}

// ================= bootstrap kernels (round 14, verbatim) =================
__global__ __launch_bounds__(256, 2) void conv3B(
    const float* __restrict__ ebuf,
    const float* __restrict__ W0, const float* __restrict__ B0,
    const float* __restrict__ W1, const float* __restrict__ B1,
    float* __restrict__ out)
{
    const int lane = threadIdx.x & 63;
    const int wv   = threadIdx.x >> 6;
    const int h  = blockIdx.y;
    const int cq = blockIdx.z & 3;
    const int z  = blockIdx.z >> 2;
    const int cout0 = cq * 16 + wv * 4;
    const float* W  = (z ? W1 : W0) + cout0 * 27;
    const float* Bv = z ? B1 : B0;

    float a[4][4] = {};
    #pragma unroll
    for (int kh = 0; kh < 3; ++kh) {
        const int r = h - 1 + kh;
        const bool valid = (r >= 0 && r < 15);
        const float msk = valid ? 1.f : 0.f;
        #pragma unroll
        for (int c = 0; c < 3; ++c) {
            const float* rr = ebuf + c * EBCS + (valid ? r : 0) * 256 + lane * 4;
            float4 v = *(const float4*)rr;
            v.x *= msk; v.y *= msk; v.z *= msk; v.w *= msk;
            float wl = __shfl_up(v.w, 1);   if (lane == 0)  wl = 0.f;
            float wr = __shfl_down(v.x, 1); if (lane == 63) wr = 0.f;
            const float win[6] = {wl, v.x, v.y, v.z, v.w, wr};
            #pragma unroll
            for (int j = 0; j < 4; ++j) {
                const float* wj = W + j * 27 + c * 9 + kh * 3;
                #pragma unroll
                for (int cc = 0; cc < 4; ++cc)
                    a[j][cc] += wj[0] * win[cc] + wj[1] * win[cc + 1] + wj[2] * win[cc + 2];
            }
        }
    }
    const int slot = (h == 0) ? TSL : (h == 14 ? BSL : (h & 15));
    float* o = out + (size_t)z * ZS1 + slot * 256;
    #pragma unroll
    for (int j = 0; j < 4; ++j) {
        const float bb = Bv[cout0 + j];
        float4 r4;
        r4.x = LEAKY(a[j][0] + bb); r4.y = LEAKY(a[j][1] + bb);
        r4.z = LEAKY(a[j][2] + bb); r4.w = LEAKY(a[j][3] + bb);
        *(float4*)(o + (cout0 + j) * CS + lane * 4) = r4;
    }
}

template<int HOUT, int HIN, int OFFI, int OFFO, int NZ>
__global__ __launch_bounds__(256, 2) void convYB(
    const float* __restrict__ in,
    const float* __restrict__ W0, const float* __restrict__ B0,
    const float* __restrict__ W1, const float* __restrict__ B1,
    float* __restrict__ out)
{
    const int lane = threadIdx.x;
    const int y    = threadIdx.y;
    const int h  = blockIdx.y;
    const int gz = blockIdx.z;
    const int z    = (NZ == 2) ? (gz >> 6) : 0;
    const int cout = (NZ == 2) ? (gz & 63) : gz;
    const float* W  = (z ? W1 : W0) + cout * 576 + y * 144;
    const float* Bv = z ? B1 : B0;
    const float* ib = in + (size_t)z * ZS1 + y * 16 * CS + lane * 4;

    int slot[3];
    #pragma unroll
    for (int t = 0; t < 3; ++t) {
        const int g = h + t;
        slot[t] = (g == 0) ? TSL : (g == HIN - 1 ? BSL : ((g + OFFI) & 15));
    }

    float acc[4] = {};
    #pragma unroll 4
    for (int c = 0; c < 16; ++c) {
        #pragma unroll
        for (int t = 0; t < 3; ++t) {
            float4 v = *(const float4*)(ib + c * CS + slot[t] * 256);
            float wl = __shfl_up(v.w, 1);   if (lane == 0)  wl = 0.f;
            float wr = __shfl_down(v.x, 1); if (lane == 63) wr = 0.f;
            const float win[6] = {wl, v.x, v.y, v.z, v.w, wr};
            const float* wj = W + c * 9 + t * 3;
            #pragma unroll
            for (int cc = 0; cc < 4; ++cc)
                acc[cc] += wj[0] * win[cc] + wj[1] * win[cc + 1] + wj[2] * win[cc + 2];
        }
    }

    __shared__ float red[4][256];
    *(float4*)&red[y][lane * 4] = *(float4*)acc;
    __syncthreads();
    const int col = y * 64 + lane;
    const int os = (h == 0) ? TSL : (h == HOUT - 1 ? BSL : ((h + OFFO) & 15));
    float v = Bv[cout] + red[0][col] + red[1][col] + red[2][col] + red[3][col];
    out[(size_t)z * ZS1 + cout * CS + os * 256 + col] = LEAKY(v);
}

__global__ __launch_bounds__(256, 2) void mmB(const float* __restrict__ L4R,
                                              float* __restrict__ MMR)
{
    const int col = threadIdx.x;
    const int r   = blockIdx.x;
    const int ig  = blockIdx.y;
    const int slot = (r == 0) ? TSL : (r == 8 ? BSL : ((r + 3) & 15));
    const float* s = L4R + slot * 256 + col;
    const float* e = L4R + ZS1 + slot * 256 + col;
    float sv[64];
    #pragma unroll
    for (int c = 0; c < 64; ++c) sv[c] = s[c * CS];
    float ev[8];
    #pragma unroll
    for (int j = 0; j < 8; ++j) ev[j] = e[(ig * 8 + j) * CS];
    #pragma unroll
    for (int k = 0; k < 8; ++k) {
        float acc = 0.f;
        #pragma unroll
        for (int j = 0; j < 8; ++j) acc += ev[j] * sv[j * 8 + k];
        MMR[(ig * 8 + k) * CS + slot * 256 + col] = acc;
    }
}

// ================= conv9 (round 14, verbatim) — used only for i=15 =================
__global__ void conv9up(const float* __restrict__ pin, const float* __restrict__ w9,
                        const float* __restrict__ b9, const float* __restrict__ x,
                        float* __restrict__ ebuf, float* __restrict__ preds, int i)
{
    const int wcol = threadIdx.x;
    const int yq   = threadIdx.y;
    const int c0   = yq * 16;
    const bool mL = (wcol > 0), mR = (wcol < 255);
    float a0 = 0.f, a1 = 0.f, a2 = 0.f;

    #pragma unroll 4
    for (int c = 0; c < 16; ++c) {
        const int cin = c0 + c;
        const float* r_ = pin + cin * 256;
        float vm = mL ? r_[wcol - 1] : 0.f;
        float v0 = r_[wcol];
        float vp = mR ? r_[wcol + 1] : 0.f;
        const float* wk0 = w9 + (0 * 64 + cin) * 9 + 3;
        const float* wk1 = w9 + (1 * 64 + cin) * 9 + 3;
        const float* wk2 = w9 + (2 * 64 + cin) * 9 + 3;
        a0 += vm * wk0[0] + v0 * wk0[1] + vp * wk0[2];
        a1 += vm * wk1[0] + v0 * wk1[1] + vp * wk1[2];
        a2 += vm * wk2[0] + v0 * wk2[1] + vp * wk2[2];
    }

    __shared__ float red[4][3][256];
    red[yq][0][wcol] = a0;
    red[yq][1][wcol] = a1;
    red[yq][2][wcol] = a2;
    __syncthreads();

    if (yq == 0) {
        #pragma unroll
        for (int j = 0; j < 3; ++j) {
            float v = b9[j] + red[0][j][wcol] + red[1][j][wcol]
                            + red[2][j][wcol] + red[3][j][wcol];
            v = LEAKY(v);
            preds[i * 768 + j * 256 + wcol] = v;
            ebuf[j * EBCS + (15 + i) * 256 + wcol] =
                x[j * EBCS + (15 + i) * 256 + wcol] - v;
        }
    }
}

// ================= finalize (round 14, verbatim) =================
__global__ void finalize(const float* __restrict__ preds, const float* __restrict__ ebuf,
                         float* __restrict__ o)
{
    const int idx = blockIdx.x * 256 + threadIdx.x;
    if (idx >= 24576) return;
    if (idx < 12288) {
        const int c = idx >> 12;
        const int t = (idx >> 8) & 15;
        const int w = idx & 255;
        o[idx] = preds[t * 768 + c * 256 + w];
    } else {
        const int j = idx - 12288;
        const int c = j >> 12;
        const int t = (j >> 8) & 15;
        const int w = j & 255;
        o[idx] = ebuf[c * EBCS + (15 + t) * 256 + w];
    }
}

extern "C" void kernel_launch(void* const* d_in, const int* in_sizes, int n_in,
                              void* d_out, int out_size, void* d_ws, size_t ws_size,
                              hipStream_t stream)
{
    const float* x   = (const float*)d_in[0];
    const float* w1x = (const float*)d_in[1];  const float* b1x = (const float*)d_in[2];
    const float* w2x = (const float*)d_in[3];  const float* b2x = (const float*)d_in[4];
    const float* w3x = (const float*)d_in[5];  const float* b3x = (const float*)d_in[6];
    const float* w4x = (const float*)d_in[7];  const float* b4x = (const float*)d_in[8];
    const float* w1e = (const float*)d_in[9];  const float* b1e = (const float*)d_in[10];
    const float* w2e = (const float*)d_in[11]; const float* b2e = (const float*)d_in[12];
    const float* w3e = (const float*)d_in[13]; const float* b3e = (const float*)d_in[14];
    const float* w4e = (const float*)d_in[15]; const float* b4e = (const float*)d_in[16];
    const float* w5  = (const float*)d_in[17]; const float* b5  = (const float*)d_in[18];
    const float* w6  = (const float*)d_in[19]; const float* b6  = (const float*)d_in[20];
    const float* w7  = (const float*)d_in[21]; const float* b7  = (const float*)d_in[22];
    const float* w8  = (const float*)d_in[23]; const float* b8  = (const float*)d_in[24];
    const float* w9  = (const float*)d_in[25]; const float* b9  = (const float*)d_in[26];

    float* ws    = (float*)d_ws;
    float* ebuf  = ws;
    float* L1R   = ebuf + 23808;
    float* L2R   = L1R + 589824;
    float* L3R   = L2R + 589824;
    float* L4R   = L3R + 589824;
    float* MMR   = L4R + 589824;
    float* L5R   = MMR + 294912;
    float* L6R   = L5R + 294912;
    float* L7b   = L6R + 294912;
    float* L8b   = L7b + 49152;
    float* preds = L8b + 16384;

    auto S2 = [](int c) { return c & 15; };
    auto r2 = [](float* b, int z, int slot) { return b + (size_t)z * ZS1 + slot * 256; };
    auto r1 = [](float* b, int slot) { return b + slot * 256; };

    hipMemcpyAsync(ebuf, x, 23808 * sizeof(float), hipMemcpyDeviceToDevice, stream);

    const dim3 cb(64, 4);

    // ---- bootstrap (step 0: L1..L6) ----
    conv3B<<<dim3(1, 15, 8), 256, 0, stream>>>(ebuf, w1x, b1x, w1e, b1e, L1R);
    convYB<13, 15, 0, 1, 2><<<dim3(1, 13, 128), cb, 0, stream>>>(L1R, w2x, b2x, w2e, b2e, L2R);
    convYB<11, 13, 1, 2, 2><<<dim3(1, 11, 128), cb, 0, stream>>>(L2R, w3x, b3x, w3e, b3e, L3R);
    convYB<9, 11, 2, 3, 2><<<dim3(1, 9, 128), cb, 0, stream>>>(L3R, w4x, b4x, w4e, b4e, L4R);
    mmB<<<dim3(9, 8), 256, 0, stream>>>(L4R, MMR);
    convYB<7, 9, 3, 4, 1><<<dim3(1, 7, 64), cb, 0, stream>>>(MMR, w5, b5, w5, b5, L5R);
    convYB<5, 7, 4, 5, 1><<<dim3(1, 5, 64), cb, 0, stream>>>(L5R, w6, b6, w6, b6, L6R);

    // ---- step-0 tail: L7(0), L8(0); conv9(0) fused into fusedL1(1) ----
    {
        const int i = 0;
        IncP p7 = {};
        p7.jd[0] = { r1(L6R, TSL),       r1(L6R, S2(i + 6)), r1(L6R, S2(i + 7)), L7b };
        p7.jd[1] = { r1(L6R, S2(i + 6)), r1(L6R, S2(i + 7)), r1(L6R, S2(i + 8)), L7b + 256 };
        p7.jd[2] = { r1(L6R, S2(i + 7)), r1(L6R, S2(i + 8)), r1(L6R, BSL),       L7b + 512 };
        convInc<<<192, cb, 0, stream>>>(p7, w7, b7, w7, b7, 0, CS, 768);
        IncP p8 = {};
        p8.jd[0] = { L7b, L7b + 256, L7b + 512, L8b };
        convInc<<<64, cb, 0, stream>>>(p8, w8, b8, w8, b8, 0, 768, 256);
    }

    for (int i = 1; i < 16; ++i) {
        // fused conv9(i-1) + L1(i)
        fusedL1<<<24, 256, 0, stream>>>(L8b, w9, b9, x, ebuf, preds,
                                        w1x, b1x, w1e, b1e, L1R, i);

        // L2
        IncP p2 = {};
        for (int z = 0; z < 2; ++z) {
            p2.jd[0 * 2 + z] = { r2(L1R, z, TSL),        r2(L1R, z, S2(i + 1)),  r2(L1R, z, S2(i + 2)),  r2(L2R, z, TSL) };
            p2.jd[1 * 2 + z] = { r2(L1R, z, S2(i + 12)), r2(L1R, z, S2(i + 13)), r2(L1R, z, BSL),        r2(L2R, z, BSL) };
            p2.jd[2 * 2 + z] = { r2(L1R, z, S2(i + 11)), r2(L1R, z, S2(i + 12)), r2(L1R, z, S2(i + 13)), r2(L2R, z, S2(i + 12)) };
        }
        convInc<<<384, cb, 0, stream>>>(p2, w2x, b2x, w2e, b2e, 42, CS, CS);

        // L3
        IncP p3i = {};
        for (int z = 0; z < 2; ++z) {
            p3i.jd[0 * 2 + z] = { r2(L2R, z, TSL),        r2(L2R, z, S2(i + 2)),  r2(L2R, z, S2(i + 3)),  r2(L3R, z, TSL) };
            p3i.jd[1 * 2 + z] = { r2(L2R, z, S2(i + 11)), r2(L2R, z, S2(i + 12)), r2(L2R, z, BSL),        r2(L3R, z, BSL) };
            p3i.jd[2 * 2 + z] = { r2(L2R, z, S2(i + 10)), r2(L2R, z, S2(i + 11)), r2(L2R, z, S2(i + 12)), r2(L3R, z, S2(i + 11)) };
        }
        convInc<<<384, cb, 0, stream>>>(p3i, w3x, b3x, w3e, b3e, 42, CS, CS);

        // L4
        IncP p4 = {};
        for (int z = 0; z < 2; ++z) {
            p4.jd[0 * 2 + z] = { r2(L3R, z, TSL),        r2(L3R, z, S2(i + 3)),  r2(L3R, z, S2(i + 4)),  r2(L4R, z, TSL) };
            p4.jd[1 * 2 + z] = { r2(L3R, z, S2(i + 10)), r2(L3R, z, S2(i + 11)), r2(L3R, z, BSL),        r2(L4R, z, BSL) };
            p4.jd[2 * 2 + z] = { r2(L3R, z, S2(i + 9)),  r2(L3R, z, S2(i + 10)), r2(L3R, z, S2(i + 11)), r2(L4R, z, S2(i + 10)) };
        }
        convInc<<<384, cb, 0, stream>>>(p4, w4x, b4x, w4e, b4e, 42, CS, CS);

        // mm (round 14, verbatim)
        MMP pm;
        pm.s[0] = r2(L4R, 0, TSL);        pm.e[0] = r2(L4R, 1, TSL);        pm.o[0] = r1(MMR, TSL);
        pm.s[1] = r2(L4R, 0, BSL);        pm.e[1] = r2(L4R, 1, BSL);        pm.o[1] = r1(MMR, BSL);
        pm.s[2] = r2(L4R, 0, S2(i + 10)); pm.e[2] = r2(L4R, 1, S2(i + 10)); pm.o[2] = r1(MMR, S2(i + 10));
        mminc<<<dim3(3, 8), 256, 0, stream>>>(pm);

        // L5 (round 14, verbatim)
        IncP p5 = {};
        p5.jd[0] = { r1(MMR, TSL),       r1(MMR, S2(i + 4)),  r1(MMR, S2(i + 5)),  r1(L5R, TSL) };
        p5.jd[1] = { r1(MMR, S2(i + 9)), r1(MMR, S2(i + 10)), r1(MMR, BSL),        r1(L5R, BSL) };
        p5.jd[2] = { r1(MMR, S2(i + 8)), r1(MMR, S2(i + 9)),  r1(MMR, S2(i + 10)), r1(L5R, S2(i + 9)) };
        convInc<<<192, cb, 0, stream>>>(p5, w5, b5, w5, b5, 0, CS, CS);

        // L6 (with round-15 T-fix)
        IncP p6 = {};
        p6.jd[0] = { r1(L5R, TSL),       r1(L5R, S2(i + 5)), r1(L5R, S2(i + 6)), r1(L6R, TSL) };
        p6.jd[1] = { r1(L5R, S2(i + 8)), r1(L5R, S2(i + 9)), r1(L5R, BSL),       r1(L6R, BSL) };
        p6.jd[2] = { r1(L5R, S2(i + 7)), r1(L5R, S2(i + 8)), r1(L5R, S2(i + 9)), r1(L6R, S2(i + 8)) };
        convInc<<<192, cb, 0, stream>>>(p6, w6, b6, w6, b6, 0, CS, CS);

        // L7
        IncP p7 = {};
        p7.jd[0] = { r1(L6R, TSL),       r1(L6R, S2(i + 6)), r1(L6R, S2(i + 7)), L7b };
        p7.jd[1] = { r1(L6R, S2(i + 6)), r1(L6R, S2(i + 7)), r1(L6R, S2(i + 8)), L7b + 256 };
        p7.jd[2] = { r1(L6R, S2(i + 7)), r1(L6R, S2(i + 8)), r1(L6R, BSL),       L7b + 512 };
        convInc<<<192, cb, 0, stream>>>(p7, w7, b7, w7, b7, 0, CS, 768);

        // L8
        IncP p8 = {};
        p8.jd[0] = { L7b, L7b + 256, L7b + 512, L8b };
        convInc<<<64, cb, 0, stream>>>(p8, w8, b8, w8, b8, 0, 768, 256);
    }

    // last step's conv9 + finalize
    conv9up<<<dim3(1, 1, 1), dim3(256, 4), 0, stream>>>(L8b, w9, b9, x, ebuf, preds, 15);
    finalize<<<96, 256, 0, stream>>>(preds, ebuf, (float*)d_out);
}

// Round 21
// 1915.737 us; speedup vs baseline: 2.0397x; 1.0637x over previous
//
#include <hip/hip_runtime.h>

#define LEAKY(v) ((v) >= 0.f ? (v) : 0.01f * (v))

#define CS   4608      // ring channel stride in floats (18 rows * 256)
#define ZS1  294912    // ring tower stride (64 * CS)
#define TSL  16        // top-pad slot
#define BSL  17        // bottom-pad slot
#define EBCS 7936      // ebuf channel stride (31*256)
#define S16(c) ((c) & 15)

// ================= generic incremental CIN=64 conv (round 14, verbatim) =================
struct JobD { const float* t0; const float* t1; const float* t2; float* o; };
struct IncP { JobD jd[6]; };

__global__ __launch_bounds__(256, 2) void convInc(
    IncP P, const float* __restrict__ W0, const float* __restrict__ B0,
    const float* __restrict__ W1, const float* __restrict__ B1,
    int zsel, int ics, int ocs)
{
    const int lane = threadIdx.x;
    const int y    = threadIdx.y;
    const int q    = blockIdx.x >> 6;
    const int cout = blockIdx.x & 63;
    const int z    = (zsel >> q) & 1;
    const float* W  = (z ? W1 : W0) + cout * 576 + y * 144;
    const float* Bv = z ? B1 : B0;
    const JobD jd  = P.jd[q];
    const int yo   = y * 16 * ics + lane * 4;
    const float* t0 = jd.t0 + yo;
    const float* t1 = jd.t1 + yo;
    const float* t2 = jd.t2 + yo;

    float acc[4] = {};
    #pragma unroll 4
    for (int c = 0; c < 16; ++c) {
        #pragma unroll
        for (int t = 0; t < 3; ++t) {
            const float* rp = (t == 0 ? t0 : (t == 1 ? t1 : t2)) + c * ics;
            float4 v = *(const float4*)rp;
            float wl = __shfl_up(v.w, 1);   if (lane == 0)  wl = 0.f;
            float wr = __shfl_down(v.x, 1); if (lane == 63) wr = 0.f;
            const float win[6] = {wl, v.x, v.y, v.z, v.w, wr};
            const float* wj = W + c * 9 + t * 3;
            #pragma unroll
            for (int cc = 0; cc < 4; ++cc)
                acc[cc] += wj[0] * win[cc] + wj[1] * win[cc + 1] + wj[2] * win[cc + 2];
        }
    }

    __shared__ float red[4][256];
    *(float4*)&red[y][lane * 4] = *(float4*)acc;
    __syncthreads();
    const int col = y * 64 + lane;
    float v = Bv[cout] + red[0][col] + red[1][col] + red[2][col] + red[3][col];
    jd.o[cout * ocs + col] = LEAKY(v);
}

// ================= fused conv9(i-1) + L1(i), (256,4) block =================
// grid 24 blocks of (256,4). Phase A: conv9up-style (yq splits cins, LDS
// reduce -> 4 dependent load groups). Phase B: 16 waves -> 16 couts.
__global__ __launch_bounds__(1024, 1) void fusedL1(
    const float* __restrict__ L8b, const float* __restrict__ w9,
    const float* __restrict__ b9, const float* __restrict__ x,
    float* __restrict__ ebuf, float* __restrict__ preds,
    const float* __restrict__ W0, const float* __restrict__ B0,
    const float* __restrict__ W1, const float* __restrict__ B1,
    float* __restrict__ L1R, int i)
{
    __shared__ float red[4][3][256];
    __shared__ float eL[3][256];
    const int wcol = threadIdx.x;       // 0..255
    const int yq   = threadIdx.y;       // 0..3

    // ---- phase A: conv9(i-1), conv9up order ----
    {
        const int c0 = yq * 16;
        const bool mL = (wcol > 0), mR = (wcol < 255);
        float a0 = 0.f, a1 = 0.f, a2 = 0.f;
        #pragma unroll 4
        for (int c = 0; c < 16; ++c) {
            const int cin = c0 + c;
            const float* r_ = L8b + cin * 256;
            float vm = mL ? r_[wcol - 1] : 0.f;
            float v0 = r_[wcol];
            float vp = mR ? r_[wcol + 1] : 0.f;
            const float* wk0 = w9 + (0 * 64 + cin) * 9 + 3;
            const float* wk1 = w9 + (1 * 64 + cin) * 9 + 3;
            const float* wk2 = w9 + (2 * 64 + cin) * 9 + 3;
            a0 += vm * wk0[0] + v0 * wk0[1] + vp * wk0[2];
            a1 += vm * wk1[0] + v0 * wk1[1] + vp * wk1[2];
            a2 += vm * wk2[0] + v0 * wk2[1] + vp * wk2[2];
        }
        red[yq][0][wcol] = a0;
        red[yq][1][wcol] = a1;
        red[yq][2][wcol] = a2;
        __syncthreads();
        if (yq == 0) {
            #pragma unroll
            for (int j = 0; j < 3; ++j) {
                float v = b9[j] + red[0][j][wcol] + red[1][j][wcol]
                                + red[2][j][wcol] + red[3][j][wcol];
                v = LEAKY(v);
                const float e = x[j * EBCS + (i + 14) * 256 + wcol] - v;
                eL[j][wcol] = e;
                if (blockIdx.x == 0) {
                    preds[(i - 1) * 768 + j * 256 + wcol] = v;
                    ebuf[j * EBCS + (i + 14) * 256 + wcol] = e;
                }
            }
        }
        __syncthreads();
    }

    // ---- phase B: conv3inc with eL override; 16 waves x 1 cout ----
    const int lane = wcol & 63;
    const int wv16 = yq * 4 + (wcol >> 6);   // 0..15
    const int job  = blockIdx.x >> 3;
    const int cq   = blockIdx.x & 3;
    const int z    = (blockIdx.x >> 2) & 1;
    const int cout = cq * 16 + wv16;
    const float* W  = (z ? W1 : W0) + cout * 27;
    const float* Bv = z ? B1 : B0;

    const float* tp[3] = {nullptr, nullptr, nullptr};
    int st[3] = {EBCS, EBCS, EBCS};
    int os;
    if (job == 0) {
        tp[1] = ebuf + i * 256;        tp[2] = ebuf + (i + 1) * 256;
        os = TSL;
    } else if (job == 1) {
        tp[0] = ebuf + (i + 13) * 256; tp[1] = &eL[0][0]; st[1] = 256;
        os = BSL;
    } else {
        tp[0] = ebuf + (i + 12) * 256; tp[1] = ebuf + (i + 13) * 256;
        tp[2] = &eL[0][0]; st[2] = 256;
        os = S16(i + 13);
    }

    float a[4] = {};
    #pragma unroll
    for (int t = 0; t < 3; ++t) {
        const float* rp = tp[t];
        if (rp) {
            #pragma unroll
            for (int c = 0; c < 3; ++c) {
                float4 v = *(const float4*)(rp + c * st[t] + lane * 4);
                float wl = __shfl_up(v.w, 1);   if (lane == 0)  wl = 0.f;
                float wr = __shfl_down(v.x, 1); if (lane == 63) wr = 0.f;
                const float win[6] = {wl, v.x, v.y, v.z, v.w, wr};
                const float* wj = W + c * 9 + t * 3;
                #pragma unroll
                for (int cc = 0; cc < 4; ++cc)
                    a[cc] += wj[0] * win[cc] + wj[1] * win[cc + 1] + wj[2] * win[cc + 2];
            }
        }
    }
    float* o = L1R + (size_t)z * ZS1 + os * 256;
    const float bb = Bv[cout];
    float4 r4;
    r4.x = LEAKY(a[0] + bb); r4.y = LEAKY(a[1] + bb);
    r4.z = LEAKY(a[2] + bb); r4.w = LEAKY(a[3] + bb);
    *(float4*)(o + cout * CS + lane * 4) = r4;
}

// ================= incremental mm (round 14, verbatim) =================
struct MMP { const float* s[3]; const float* e[3]; float* o[3]; };
__global__ __launch_bounds__(256, 2) void mminc(MMP P)
{
    const int col = threadIdx.x;
    const int job = blockIdx.x;
    const int ig  = blockIdx.y;
    const float* s = P.s[job] + col;
    const float* e = P.e[job] + col;
    float sv[64];
    #pragma unroll
    for (int c = 0; c < 64; ++c) sv[c] = s[c * CS];
    float ev[8];
    #pragma unroll
    for (int j = 0; j < 8; ++j) ev[j] = e[(ig * 8 + j) * CS];
    float* o = P.o[job];
    #pragma unroll
    for (int k = 0; k < 8; ++k) {
        float acc = 0.f;
        #pragma unroll
        for (int j = 0; j < 8; ++j) acc += ev[j] * sv[j * 8 + k];
        o[(ig * 8 + k) * CS + col] = acc;
    }
}

// ================= bootstrap kernels (round 14, verbatim) =================
__global__ __launch_bounds__(256, 2) void conv3B(
    const float* __restrict__ ebuf,
    const float* __restrict__ W0, const float* __restrict__ B0,
    const float* __restrict__ W1, const float* __restrict__ B1,
    float* __restrict__ out)
{
    const int lane = threadIdx.x & 63;
    const int wv   = threadIdx.x >> 6;
    const int h  = blockIdx.y;
    const int cq = blockIdx.z & 3;
    const int z  = blockIdx.z >> 2;
    const int cout0 = cq * 16 + wv * 4;
    const float* W  = (z ? W1 : W0) + cout0 * 27;
    const float* Bv = z ? B1 : B0;

    float a[4][4] = {};
    #pragma unroll
    for (int kh = 0; kh < 3; ++kh) {
        const int r = h - 1 + kh;
        const bool valid = (r >= 0 && r < 15);
        const float msk = valid ? 1.f : 0.f;
        #pragma unroll
        for (int c = 0; c < 3; ++c) {
            const float* rr = ebuf + c * EBCS + (valid ? r : 0) * 256 + lane * 4;
            float4 v = *(const float4*)rr;
            v.x *= msk; v.y *= msk; v.z *= msk; v.w *= msk;
            float wl = __shfl_up(v.w, 1);   if (lane == 0)  wl = 0.f;
            float wr = __shfl_down(v.x, 1); if (lane == 63) wr = 0.f;
            const float win[6] = {wl, v.x, v.y, v.z, v.w, wr};
            #pragma unroll
            for (int j = 0; j < 4; ++j) {
                const float* wj = W + j * 27 + c * 9 + kh * 3;
                #pragma unroll
                for (int cc = 0; cc < 4; ++cc)
                    a[j][cc] += wj[0] * win[cc] + wj[1] * win[cc + 1] + wj[2] * win[cc + 2];
            }
        }
    }
    const int slot = (h == 0) ? TSL : (h == 14 ? BSL : (h & 15));
    float* o = out + (size_t)z * ZS1 + slot * 256;
    #pragma unroll
    for (int j = 0; j < 4; ++j) {
        const float bb = Bv[cout0 + j];
        float4 r4;
        r4.x = LEAKY(a[j][0] + bb); r4.y = LEAKY(a[j][1] + bb);
        r4.z = LEAKY(a[j][2] + bb); r4.w = LEAKY(a[j][3] + bb);
        *(float4*)(o + (cout0 + j) * CS + lane * 4) = r4;
    }
}

template<int HOUT, int HIN, int OFFI, int OFFO, int NZ>
__global__ __launch_bounds__(256, 2) void convYB(
    const float* __restrict__ in,
    const float* __restrict__ W0, const float* __restrict__ B0,
    const float* __restrict__ W1, const float* __restrict__ B1,
    float* __restrict__ out)
{
    const int lane = threadIdx.x;
    const int y    = threadIdx.y;
    const int h  = blockIdx.y;
    const int gz = blockIdx.z;
    const int z    = (NZ == 2) ? (gz >> 6) : 0;
    const int cout = (NZ == 2) ? (gz & 63) : gz;
    const float* W  = (z ? W1 : W0) + cout * 576 + y * 144;
    const float* Bv = z ? B1 : B0;
    const float* ib = in + (size_t)z * ZS1 + y * 16 * CS + lane * 4;

    int slot[3];
    #pragma unroll
    for (int t = 0; t < 3; ++t) {
        const int g = h + t;
        slot[t] = (g == 0) ? TSL : (g == HIN - 1 ? BSL : ((g + OFFI) & 15));
    }

    float acc[4] = {};
    #pragma unroll 4
    for (int c = 0; c < 16; ++c) {
        #pragma unroll
        for (int t = 0; t < 3; ++t) {
            float4 v = *(const float4*)(ib + c * CS + slot[t] * 256);
            float wl = __shfl_up(v.w, 1);   if (lane == 0)  wl = 0.f;
            float wr = __shfl_down(v.x, 1); if (lane == 63) wr = 0.f;
            const float win[6] = {wl, v.x, v.y, v.z, v.w, wr};
            const float* wj = W + c * 9 + t * 3;
            #pragma unroll
            for (int cc = 0; cc < 4; ++cc)
                acc[cc] += wj[0] * win[cc] + wj[1] * win[cc + 1] + wj[2] * win[cc + 2];
        }
    }

    __shared__ float red[4][256];
    *(float4*)&red[y][lane * 4] = *(float4*)acc;
    __syncthreads();
    const int col = y * 64 + lane;
    const int os = (h == 0) ? TSL : (h == HOUT - 1 ? BSL : ((h + OFFO) & 15));
    float v = Bv[cout] + red[0][col] + red[1][col] + red[2][col] + red[3][col];
    out[(size_t)z * ZS1 + cout * CS + os * 256 + col] = LEAKY(v);
}

__global__ __launch_bounds__(256, 2) void mmB(const float* __restrict__ L4R,
                                              float* __restrict__ MMR)
{
    const int col = threadIdx.x;
    const int r   = blockIdx.x;
    const int ig  = blockIdx.y;
    const int slot = (r == 0) ? TSL : (r == 8 ? BSL : ((r + 3) & 15));
    const float* s = L4R + slot * 256 + col;
    const float* e = L4R + ZS1 + slot * 256 + col;
    float sv[64];
    #pragma unroll
    for (int c = 0; c < 64; ++c) sv[c] = s[c * CS];
    float ev[8];
    #pragma unroll
    for (int j = 0; j < 8; ++j) ev[j] = e[(ig * 8 + j) * CS];
    #pragma unroll
    for (int k = 0; k < 8; ++k) {
        float acc = 0.f;
        #pragma unroll
        for (int j = 0; j < 8; ++j) acc += ev[j] * sv[j * 8 + k];
        MMR[(ig * 8 + k) * CS + slot * 256 + col] = acc;
    }
}

// ================= conv9(15) + finalize, single block (256,4) =================
__global__ __launch_bounds__(1024, 1) void conv9fin(
    const float* __restrict__ pin, const float* __restrict__ w9,
    const float* __restrict__ b9, const float* __restrict__ x,
    float* __restrict__ ebuf, float* __restrict__ preds,
    float* __restrict__ out)
{
    const int i = 15;
    __shared__ float red[4][3][256];
    __shared__ float pr[3][256];
    __shared__ float es[3][256];
    const int wcol = threadIdx.x;
    const int yq   = threadIdx.y;
    const int c0   = yq * 16;
    const bool mL = (wcol > 0), mR = (wcol < 255);
    float a0 = 0.f, a1 = 0.f, a2 = 0.f;

    #pragma unroll 4
    for (int c = 0; c < 16; ++c) {
        const int cin = c0 + c;
        const float* r_ = pin + cin * 256;
        float vm = mL ? r_[wcol - 1] : 0.f;
        float v0 = r_[wcol];
        float vp = mR ? r_[wcol + 1] : 0.f;
        const float* wk0 = w9 + (0 * 64 + cin) * 9 + 3;
        const float* wk1 = w9 + (1 * 64 + cin) * 9 + 3;
        const float* wk2 = w9 + (2 * 64 + cin) * 9 + 3;
        a0 += vm * wk0[0] + v0 * wk0[1] + vp * wk0[2];
        a1 += vm * wk1[0] + v0 * wk1[1] + vp * wk1[2];
        a2 += vm * wk2[0] + v0 * wk2[1] + vp * wk2[2];
    }

    red[yq][0][wcol] = a0;
    red[yq][1][wcol] = a1;
    red[yq][2][wcol] = a2;
    __syncthreads();

    if (yq == 0) {
        #pragma unroll
        for (int j = 0; j < 3; ++j) {
            float v = b9[j] + red[0][j][wcol] + red[1][j][wcol]
                            + red[2][j][wcol] + red[3][j][wcol];
            v = LEAKY(v);
            const float e = x[j * EBCS + (15 + i) * 256 + wcol] - v;
            pr[j][wcol] = v;
            es[j][wcol] = e;
            preds[i * 768 + j * 256 + wcol] = v;
            ebuf[j * EBCS + (15 + i) * 256 + wcol] = e;
        }
    }
    __syncthreads();

    // finalize: d_out = [pred (3,16,256) | truth (3,16,256)]; row 15 from LDS
    const int flat = yq * 256 + wcol;
    for (int idx = flat; idx < 24576; idx += 1024) {
        if (idx < 12288) {
            const int c = idx >> 12;
            const int t = (idx >> 8) & 15;
            const int w = idx & 255;
            out[idx] = (t == 15) ? pr[c][w] : preds[t * 768 + c * 256 + w];
        } else {
            const int j = idx - 12288;
            const int c = j >> 12;
            const int t = (j >> 8) & 15;
            const int w = j & 255;
            out[idx] = (t == 15) ? es[c][w] : ebuf[c * EBCS + (15 + t) * 256 + w];
        }
    }
}

extern "C" void kernel_launch(void* const* d_in, const int* in_sizes, int n_in,
                              void* d_out, int out_size, void* d_ws, size_t ws_size,
                              hipStream_t stream)
{
    const float* x   = (const float*)d_in[0];
    const float* w1x = (const float*)d_in[1];  const float* b1x = (const float*)d_in[2];
    const float* w2x = (const float*)d_in[3];  const float* b2x = (const float*)d_in[4];
    const float* w3x = (const float*)d_in[5];  const float* b3x = (const float*)d_in[6];
    const float* w4x = (const float*)d_in[7];  const float* b4x = (const float*)d_in[8];
    const float* w1e = (const float*)d_in[9];  const float* b1e = (const float*)d_in[10];
    const float* w2e = (const float*)d_in[11]; const float* b2e = (const float*)d_in[12];
    const float* w3e = (const float*)d_in[13]; const float* b3e = (const float*)d_in[14];
    const float* w4e = (const float*)d_in[15]; const float* b4e = (const float*)d_in[16];
    const float* w5  = (const float*)d_in[17]; const float* b5  = (const float*)d_in[18];
    const float* w6  = (const float*)d_in[19]; const float* b6  = (const float*)d_in[20];
    const float* w7  = (const float*)d_in[21]; const float* b7  = (const float*)d_in[22];
    const float* w8  = (const float*)d_in[23]; const float* b8  = (const float*)d_in[24];
    const float* w9  = (const float*)d_in[25]; const float* b9  = (const float*)d_in[26];

    float* ws    = (float*)d_ws;
    float* ebuf  = ws;
    float* L1R   = ebuf + 23808;
    float* L2R   = L1R + 589824;
    float* L3R   = L2R + 589824;
    float* L4R   = L3R + 589824;
    float* MMR   = L4R + 589824;
    float* L5R   = MMR + 294912;
    float* L6R   = L5R + 294912;
    float* L7b   = L6R + 294912;
    float* L8b   = L7b + 49152;
    float* preds = L8b + 16384;

    auto S2 = [](int c) { return c & 15; };
    auto r2 = [](float* b, int z, int slot) { return b + (size_t)z * ZS1 + slot * 256; };
    auto r1 = [](float* b, int slot) { return b + slot * 256; };

    hipMemcpyAsync(ebuf, x, 23808 * sizeof(float), hipMemcpyDeviceToDevice, stream);

    const dim3 cb(64, 4);
    const dim3 fb(256, 4);

    // ---- bootstrap (step 0: L1..L6) ----
    conv3B<<<dim3(1, 15, 8), 256, 0, stream>>>(ebuf, w1x, b1x, w1e, b1e, L1R);
    convYB<13, 15, 0, 1, 2><<<dim3(1, 13, 128), cb, 0, stream>>>(L1R, w2x, b2x, w2e, b2e, L2R);
    convYB<11, 13, 1, 2, 2><<<dim3(1, 11, 128), cb, 0, stream>>>(L2R, w3x, b3x, w3e, b3e, L3R);
    convYB<9, 11, 2, 3, 2><<<dim3(1, 9, 128), cb, 0, stream>>>(L3R, w4x, b4x, w4e, b4e, L4R);
    mmB<<<dim3(9, 8), 256, 0, stream>>>(L4R, MMR);
    convYB<7, 9, 3, 4, 1><<<dim3(1, 7, 64), cb, 0, stream>>>(MMR, w5, b5, w5, b5, L5R);
    convYB<5, 7, 4, 5, 1><<<dim3(1, 5, 64), cb, 0, stream>>>(L5R, w6, b6, w6, b6, L6R);

    // ---- step-0 tail: L7(0), L8(0); conv9(0) fused into fusedL1(1) ----
    {
        const int i = 0;
        IncP p7 = {};
        p7.jd[0] = { r1(L6R, TSL),       r1(L6R, S2(i + 6)), r1(L6R, S2(i + 7)), L7b };
        p7.jd[1] = { r1(L6R, S2(i + 6)), r1(L6R, S2(i + 7)), r1(L6R, S2(i + 8)), L7b + 256 };
        p7.jd[2] = { r1(L6R, S2(i + 7)), r1(L6R, S2(i + 8)), r1(L6R, BSL),       L7b + 512 };
        convInc<<<192, cb, 0, stream>>>(p7, w7, b7, w7, b7, 0, CS, 768);
        IncP p8 = {};
        p8.jd[0] = { L7b, L7b + 256, L7b + 512, L8b };
        convInc<<<64, cb, 0, stream>>>(p8, w8, b8, w8, b8, 0, 768, 256);
    }

    for (int i = 1; i < 16; ++i) {
        // fused conv9(i-1) + L1(i)
        fusedL1<<<24, fb, 0, stream>>>(L8b, w9, b9, x, ebuf, preds,
                                       w1x, b1x, w1e, b1e, L1R, i);

        // L2
        IncP p2 = {};
        for (int z = 0; z < 2; ++z) {
            p2.jd[0 * 2 + z] = { r2(L1R, z, TSL),        r2(L1R, z, S2(i + 1)),  r2(L1R, z, S2(i + 2)),  r2(L2R, z, TSL) };
            p2.jd[1 * 2 + z] = { r2(L1R, z, S2(i + 12)), r2(L1R, z, S2(i + 13)), r2(L1R, z, BSL),        r2(L2R, z, BSL) };
            p2.jd[2 * 2 + z] = { r2(L1R, z, S2(i + 11)), r2(L1R, z, S2(i + 12)), r2(L1R, z, S2(i + 13)), r2(L2R, z, S2(i + 12)) };
        }
        convInc<<<384, cb, 0, stream>>>(p2, w2x, b2x, w2e, b2e, 42, CS, CS);

        // L3
        IncP p3i = {};
        for (int z = 0; z < 2; ++z) {
            p3i.jd[0 * 2 + z] = { r2(L2R, z, TSL),        r2(L2R, z, S2(i + 2)),  r2(L2R, z, S2(i + 3)),  r2(L3R, z, TSL) };
            p3i.jd[1 * 2 + z] = { r2(L2R, z, S2(i + 11)), r2(L2R, z, S2(i + 12)), r2(L2R, z, BSL),        r2(L3R, z, BSL) };
            p3i.jd[2 * 2 + z] = { r2(L2R, z, S2(i + 10)), r2(L2R, z, S2(i + 11)), r2(L2R, z, S2(i + 12)), r2(L3R, z, S2(i + 11)) };
        }
        convInc<<<384, cb, 0, stream>>>(p3i, w3x, b3x, w3e, b3e, 42, CS, CS);

        // L4
        IncP p4 = {};
        for (int z = 0; z < 2; ++z) {
            p4.jd[0 * 2 + z] = { r2(L3R, z, TSL),        r2(L3R, z, S2(i + 3)),  r2(L3R, z, S2(i + 4)),  r2(L4R, z, TSL) };
            p4.jd[1 * 2 + z] = { r2(L3R, z, S2(i + 10)), r2(L3R, z, S2(i + 11)), r2(L3R, z, BSL),        r2(L4R, z, BSL) };
            p4.jd[2 * 2 + z] = { r2(L3R, z, S2(i + 9)),  r2(L3R, z, S2(i + 10)), r2(L3R, z, S2(i + 11)), r2(L4R, z, S2(i + 10)) };
        }
        convInc<<<384, cb, 0, stream>>>(p4, w4x, b4x, w4e, b4e, 42, CS, CS);

        // mm
        MMP pm;
        pm.s[0] = r2(L4R, 0, TSL);        pm.e[0] = r2(L4R, 1, TSL);        pm.o[0] = r1(MMR, TSL);
        pm.s[1] = r2(L4R, 0, BSL);        pm.e[1] = r2(L4R, 1, BSL);        pm.o[1] = r1(MMR, BSL);
        pm.s[2] = r2(L4R, 0, S2(i + 10)); pm.e[2] = r2(L4R, 1, S2(i + 10)); pm.o[2] = r1(MMR, S2(i + 10));
        mminc<<<dim3(3, 8), 256, 0, stream>>>(pm);

        // L5
        IncP p5 = {};
        p5.jd[0] = { r1(MMR, TSL),       r1(MMR, S2(i + 4)),  r1(MMR, S2(i + 5)),  r1(L5R, TSL) };
        p5.jd[1] = { r1(MMR, S2(i + 9)), r1(MMR, S2(i + 10)), r1(MMR, BSL),        r1(L5R, BSL) };
        p5.jd[2] = { r1(MMR, S2(i + 8)), r1(MMR, S2(i + 9)),  r1(MMR, S2(i + 10)), r1(L5R, S2(i + 9)) };
        convInc<<<192, cb, 0, stream>>>(p5, w5, b5, w5, b5, 0, CS, CS);

        // L6
        IncP p6 = {};
        p6.jd[0] = { r1(L5R, TSL),       r1(L5R, S2(i + 5)), r1(L5R, S2(i + 6)), r1(L6R, TSL) };
        p6.jd[1] = { r1(L5R, S2(i + 8)), r1(L5R, S2(i + 9)), r1(L5R, BSL),       r1(L6R, BSL) };
        p6.jd[2] = { r1(L5R, S2(i + 7)), r1(L5R, S2(i + 8)), r1(L5R, S2(i + 9)), r1(L6R, S2(i + 8)) };
        convInc<<<192, cb, 0, stream>>>(p6, w6, b6, w6, b6, 0, CS, CS);

        // L7
        IncP p7 = {};
        p7.jd[0] = { r1(L6R, TSL),       r1(L6R, S2(i + 6)), r1(L6R, S2(i + 7)), L7b };
        p7.jd[1] = { r1(L6R, S2(i + 6)), r1(L6R, S2(i + 7)), r1(L6R, S2(i + 8)), L7b + 256 };
        p7.jd[2] = { r1(L6R, S2(i + 7)), r1(L6R, S2(i + 8)), r1(L6R, BSL),       L7b + 512 };
        convInc<<<192, cb, 0, stream>>>(p7, w7, b7, w7, b7, 0, CS, 768);

        // L8
        IncP p8 = {};
        p8.jd[0] = { L7b, L7b + 256, L7b + 512, L8b };
        convInc<<<64, cb, 0, stream>>>(p8, w8, b8, w8, b8, 0, 768, 256);
    }

    // conv9(15) + finalize, one dispatch
    conv9fin<<<1, fb, 0, stream>>>(L8b, w9, b9, x, ebuf, preds, (float*)d_out);
}